// Round 11
// baseline (196.578 us; speedup 1.0000x reference)
//
#include <hip/hip_runtime.h>

// Problem constants: B=4, T=2048, D=1024, H=16, DK=64, M = B*T = 8192.
// Workspace layout (bytes):
//   xb  @ 0         : x as fp16            (16 MB)
//   wt  @ 16 MB     : Wq,Wk,Wv,Wo transposed [N][K] fp16 (4 x 2 MB)
//   q   @ 24 MB     : Q (pre-scaled by log2e/8) [B*T, D] fp16 (16 MB)
//   k   @ 40 MB     : K  [B*T, D] fp16     (16 MB)
//   vt  @ 72 MB     : V^T [B*H][64][T] fp16(16 MB)  <- written by QKV epilogue
//   cx  @ 88 MB     : attention ctx fp16   (16 MB)
//   y   @ 104 MB    : pre-LN f32           (32 MB)

using u16 = unsigned short;
using u32 = unsigned int;
typedef _Float16 f16x8 __attribute__((ext_vector_type(8)));
typedef float f32x4 __attribute__((ext_vector_type(4)));
typedef unsigned short u16x8 __attribute__((ext_vector_type(8)));

template <bool B> struct BoolTag { static constexpr bool v = B; };

__device__ inline u16 f2h_bits(float f) {
    _Float16 h = (_Float16)f;
    return __builtin_bit_cast(u16, h);
}

__device__ __forceinline__ void gload16(const void* g, void* l) {
    __builtin_amdgcn_global_load_lds(
        (const __attribute__((address_space(1))) void*)g,
        (__attribute__((address_space(3))) void*)l, 16, 0, 0);
}

// -------------------------- fused converts: x -> fp16, W^T x4 -> fp16
// blocks 0..4095: x;  blocks 4096..5119: weight tiles (z = wb>>8).
__global__ __launch_bounds__(256) void convert_kernel(
    const float* __restrict__ x, u16* __restrict__ xb,
    const float* __restrict__ W0, const float* __restrict__ W1,
    const float* __restrict__ W2, const float* __restrict__ W3,
    u16* __restrict__ Wt) {
    __shared__ float ts[64][68];
    const int bid = blockIdx.x, tid = threadIdx.x;
    if (bid < 4096) {
        size_t i = ((size_t)bid * 256 + tid) * 8;
        float4 a = *(const float4*)(x + i);
        float4 b = *(const float4*)(x + i + 4);
        u16x8 o;
        o[0] = f2h_bits(a.x); o[1] = f2h_bits(a.y); o[2] = f2h_bits(a.z); o[3] = f2h_bits(a.w);
        o[4] = f2h_bits(b.x); o[5] = f2h_bits(b.y); o[6] = f2h_bits(b.z); o[7] = f2h_bits(b.w);
        *(u16x8*)(xb + i) = o;
        return;
    }
    const int wb = bid - 4096;
    const int z = wb >> 8, rem = wb & 255;
    const float* W = z == 0 ? W0 : (z == 1 ? W1 : (z == 2 ? W2 : W3));
    u16* Wo = Wt + (size_t)z * 1048576;
    const int k0 = (rem >> 4) * 64, n0 = (rem & 15) * 64;
    const int rr = tid >> 3, c = tid & 7;
#pragma unroll
    for (int p = 0; p < 2; p++) {
        int k = p * 32 + rr;
        float4 u = *(const float4*)(W + (size_t)(k0 + k) * 1024 + n0 + c * 8);
        float4 w = *(const float4*)(W + (size_t)(k0 + k) * 1024 + n0 + c * 8 + 4);
        *(float4*)&ts[k][c * 8] = u;
        *(float4*)&ts[k][c * 8 + 4] = w;
    }
    __syncthreads();
#pragma unroll
    for (int p = 0; p < 2; p++) {
        int n = p * 32 + rr;
        u16 o[8];
#pragma unroll
        for (int j = 0; j < 8; j++) o[j] = f2h_bits(ts[c * 8 + j][n]);
        *(u16x8*)(Wo + (size_t)(n0 + n) * 1024 + k0 + c * 8) = *(u16x8*)o;
    }
}

// --------------------------------------------------------- 128x256 GEMM
// C[M,N] = A[M,1024] @ W (W as Wt[N][1024] fp16). BM=128, BN=256, BK=64.
// 512 threads = 8 waves (2M x 4N), per-wave 64x64. Triple-buffered LDS,
// m201-style phases, counted vmcnt(6) per K-tile.
// MODE 0: QKV fused (N=3072): Q/K fp16 out + bias (+log2e/8 scale on Q);
//         V blocks transpose in-LDS (stride 134: bank 3*l15, 2-way max)
//         and write vt[(b*16+h)*64+d][t] directly.
// MODE 1: Wo (N=1024), f32 out + bias + residual.
template <int MODE>
__global__ __launch_bounds__(512) void gemm256_kernel(
    const u16* __restrict__ A, const u16* __restrict__ Wt,
    const float* __restrict__ b0, const float* __restrict__ b1,
    const float* __restrict__ b2, u16* __restrict__ qo, u16* __restrict__ ko,
    u16* __restrict__ vt, float* __restrict__ outf,
    const float* __restrict__ xres) {
    constexpr int NBY = (MODE == 0) ? 12 : 4;
    __shared__ u16 As[3][128 * 64];
    __shared__ u16 Bs[3][256 * 64];

    const int bid = blockIdx.x;
    const int cpx = (MODE == 0) ? 96 : 32;        // gridDim/8, grid%8==0
    const int swz = (bid & 7) * cpx + (bid >> 3); // XCD-contiguous
    const int bx = swz / NBY, by = swz % NBY;
    const size_t row0 = (size_t)bx * 128;
    const size_t col0 = (size_t)by * 256;

    const int tid = threadIdx.x, lane = tid & 63;
    const int wid = tid >> 6, wm = wid >> 2, wn = wid & 3;
    const int l15 = lane & 15, lg = lane >> 4;
    const int rr = tid >> 3, c8 = tid & 7;
    const int scw = (c8 ^ (rr & 7)) * 8;          // pre-swizzled source chunk

    f32x4 acc[4][4] = {};

    auto stage_half = [&](int kt, u16* dA, u16* dB, int h) {
        const int k0 = kt * 64;
        if (h == 0) {
            gload16(A + (row0 + rr) * 1024 + k0 + scw, dA + tid * 8);
            gload16(Wt + (col0 + rr) * 1024 + k0 + scw, dB + tid * 8);
            gload16(Wt + (col0 + 64 + rr) * 1024 + k0 + scw, dB + (512 + tid) * 8);
        } else {
            gload16(A + (row0 + 64 + rr) * 1024 + k0 + scw, dA + (512 + tid) * 8);
            gload16(Wt + (col0 + 128 + rr) * 1024 + k0 + scw, dB + (1024 + tid) * 8);
            gload16(Wt + (col0 + 192 + rr) * 1024 + k0 + scw, dB + (1536 + tid) * 8);
        }
    };

    auto ldops = [&](const u16* bA, const u16* bB, int kcv, f16x8* Af, f16x8* Bf) {
        const int swo = ((kcv * 4 + lg) ^ (l15 & 7)) * 8;
#pragma unroll
        for (int n = 0; n < 4; n++)
            Bf[n] = *(const f16x8*)(bB + (wn * 64 + n * 16 + l15) * 64 + swo);
#pragma unroll
        for (int m = 0; m < 4; m++)
            Af[m] = *(const f16x8*)(bA + (wm * 64 + m * 16 + l15) * 64 + swo);
    };

    auto domfma = [&](const f16x8* Af, const f16x8* Bf) {
        __builtin_amdgcn_s_setprio(1);
#pragma unroll
        for (int m = 0; m < 4; m++)
#pragma unroll
            for (int n = 0; n < 4; n++)
                acc[m][n] = __builtin_amdgcn_mfma_f32_16x16x32_f16(
                    Af[m], Bf[n], acc[m][n], 0, 0, 0);
        __builtin_amdgcn_s_setprio(0);
    };

    u16 *pA = &As[0][0], *pnA = &As[1][0], *ppA = &As[2][0];
    u16 *pB = &Bs[0][0], *pnB = &Bs[1][0], *ppB = &Bs[2][0];

    stage_half(0, pA, pB, 0);
    stage_half(0, pA, pB, 1);
    stage_half(1, pnA, pnB, 0);
    stage_half(1, pnA, pnB, 1);
    asm volatile("s_waitcnt vmcnt(6)" ::: "memory");
    __builtin_amdgcn_sched_barrier(0);
    __builtin_amdgcn_s_barrier();

#pragma unroll 1
    for (int t = 0; t < 16; t++) {
        f16x8 af[4], bf[4];
        ldops(pA, pB, 0, af, bf);
        if (t < 14) stage_half(t + 2, ppA, ppB, 0);
        __builtin_amdgcn_sched_barrier(0);
        __builtin_amdgcn_s_barrier();
        asm volatile("s_waitcnt lgkmcnt(0)" ::: "memory");
        __builtin_amdgcn_sched_barrier(0);
        domfma(af, bf);
        __builtin_amdgcn_sched_barrier(0);
        __builtin_amdgcn_s_barrier();
        ldops(pA, pB, 1, af, bf);
        if (t < 14) stage_half(t + 2, ppA, ppB, 1);
        if (t < 14)       asm volatile("s_waitcnt vmcnt(6)" ::: "memory");
        else if (t == 14) asm volatile("s_waitcnt vmcnt(0)" ::: "memory");
        __builtin_amdgcn_sched_barrier(0);
        __builtin_amdgcn_s_barrier();
        asm volatile("s_waitcnt lgkmcnt(0)" ::: "memory");
        __builtin_amdgcn_sched_barrier(0);
        domfma(af, bf);
        __builtin_amdgcn_sched_barrier(0);
        if (t < 15) {
            __builtin_amdgcn_s_barrier();
            u16* tp;
            tp = pA; pA = pnA; pnA = ppA; ppA = tp;
            tp = pB; pB = pnB; pnB = ppB; ppB = tp;
        }
    }

    if (MODE == 0) {
        const int zsel = by >> 2;  // 0=Q, 1=K, 2=V
        if (zsel < 2) {
            u16* ob = zsel == 0 ? qo : ko;
            const float* bias = zsel == 0 ? b0 : b1;
            const float qs = zsel == 0 ? 0.18033688f : 1.0f;  // log2(e)/8 on Q
#pragma unroll
            for (int m = 0; m < 4; m++) {
#pragma unroll
                for (int n = 0; n < 4; n++) {
                    size_t col = col0 + wn * 64 + n * 16 + l15;
                    size_t colz = col & 1023;
                    float bb = bias[colz];
#pragma unroll
                    for (int r = 0; r < 4; r++) {
                        size_t row = row0 + wm * 64 + m * 16 + lg * 4 + r;
                        ob[row * 1024 + colz] = f2h_bits((acc[m][n][r] + bb) * qs);
                    }
                }
            }
        } else {
            // V: bias + in-LDS transpose -> vt[(b*16+h)*64+d][t]
            u16* TL = &Bs[0][0];  // [256][134] u16 = 68608 B (Bs is 98304 B)
            __syncthreads();
#pragma unroll
            for (int m = 0; m < 4; m++) {
#pragma unroll
                for (int n = 0; n < 4; n++) {
                    int cl = wn * 64 + n * 16 + l15;
                    float bb = b2[(col0 & 1023) + cl];
#pragma unroll
                    for (int r = 0; r < 4; r++) {
                        int rl = wm * 64 + m * 16 + lg * 4 + r;
                        TL[cl * 134 + rl] = f2h_bits(acc[m][n][r] + bb);
                    }
                }
            }
            __syncthreads();
            const int vrl = tid >> 1, th = tid & 1;
            size_t vrow = (row0 >> 11) * 1024 + (col0 & 1023) + vrl;
            const int t0loc = (int)(row0 & 2047) + th * 64;
#pragma unroll
            for (int j = 0; j < 8; j++)
                *(u16x8*)(vt + vrow * 2048 + t0loc + j * 8) =
                    *(const u16x8*)(TL + vrl * 134 + th * 64 + j * 8);
        }
    } else {
#pragma unroll
        for (int m = 0; m < 4; m++) {
#pragma unroll
            for (int n = 0; n < 4; n++) {
                size_t col = col0 + wn * 64 + n * 16 + l15;
                float bb = b0[col];
#pragma unroll
                for (int r = 0; r < 4; r++) {
                    size_t row = row0 + wm * 64 + m * 16 + lg * 4 + r;
                    size_t idx = row * 1024 + col;
                    outf[idx] = acc[m][n][r] + bb + xres[idx];
                }
            }
        }
    }
}

// ------------------------------------------------------------- attention v7
// 8 waves x 32 q = 256 q/block, KV steps of 64, grid (64 bh, 8 qb) = 512
// blocks, 2 blocks/CU. WORK-BALANCED qb map: first dispatch round gets
// {32,28,24,20}-step strips, backfill round {4,8,12,16} -> co-resident sum
// ~uniform 36 steps. exp2-direct softmax (scale folded into Q), swapped
// QK^T (mfma(K,Q)), cvt_pkrtz packed P into padded [16][72] P-LDS.
__global__ __launch_bounds__(512) void attn_kernel(const u16* __restrict__ Q,
                                                   const u16* __restrict__ Kb,
                                                   const u16* __restrict__ Vt,
                                                   u16* __restrict__ ctx) {
    __shared__ u16 Ks[2][64 * 64];
    __shared__ u16 Vs[2][64 * 64];
    __shared__ u16 Ps[8][2][16][72];

    const int bh = blockIdx.x;
    const int b = bh >> 4, h = bh & 15;
    const int byv = (int)blockIdx.y;
    const int qb = byv < 4 ? 7 - byv : byv - 4;  // balanced big/small pairing
    const int tid = threadIdx.x, lane = tid & 63, wid = tid >> 6;
    const int l15 = lane & 15, lg = lane >> 4;
    const int q0w = qb * 256 + wid * 32;
    const int send = qb * 256;

    const int rr = tid >> 3, c8 = tid & 7;
    const int scw = (c8 ^ (rr & 7)) * 8;
    const size_t kbase = ((size_t)b * 2048) * 1024 + h * 64 + scw;
    const size_t vbase = ((size_t)bh * 64 + rr) * 2048 + scw;

    f16x8 qv[2][2];
#pragma unroll
    for (int qf = 0; qf < 2; qf++) {
        size_t qoff = ((size_t)b * 2048 + q0w + qf * 16 + l15) * 1024 + h * 64 + lg * 8;
        qv[qf][0] = *(const f16x8*)(Q + qoff);
        qv[qf][1] = *(const f16x8*)(Q + qoff + 32);
    }

    const int swk0 = (lg ^ (l15 & 7)) * 8;
    const int swk1 = ((4 + lg) ^ (l15 & 7)) * 8;
    u16* Pw0 = &Ps[wid][0][0][0] + l15 * 72;
    u16* Pw1 = &Ps[wid][1][0][0] + l15 * 72;

    f32x4 acc[2][4] = {};
    float psum[2] = {0.0f, 0.0f};

    auto stage = [&](int s, int bf) {
        gload16(Kb + kbase + (size_t)(s + rr) * 1024, Ks[bf] + tid * 8);
        gload16(Vt + vbase + s, Vs[bf] + tid * 8);
    };

    auto body = [&](int s, int bf, auto maskc) {
        constexpr bool MASK = decltype(maskc)::v;
        f32x4 sc[2][4];
#pragma unroll
        for (int c = 0; c < 4; c++) {
            const u16* kp = Ks[bf] + (c * 16 + l15) * 64;
            f16x8 kf0 = *(const f16x8*)(kp + swk0);
            f16x8 kf1 = *(const f16x8*)(kp + swk1);
#pragma unroll
            for (int qf = 0; qf < 2; qf++) {
                f32x4 z = {};
                z = __builtin_amdgcn_mfma_f32_16x16x32_f16(kf0, qv[qf][0], z, 0, 0, 0);
                z = __builtin_amdgcn_mfma_f32_16x16x32_f16(kf1, qv[qf][1], z, 0, 0, 0);
                sc[qf][c] = z;
            }
        }
#pragma unroll
        for (int qf = 0; qf < 2; qf++) {
            u16* Pw = qf ? Pw1 : Pw0;
#pragma unroll
            for (int c = 0; c < 4; c++) {
                float pv[4];
#pragma unroll
                for (int r = 0; r < 4; r++) {
                    float e = __builtin_amdgcn_exp2f(fminf(sc[qf][c][r], 15.0f));
                    if (MASK) {
                        int kk = s + c * 16 + lg * 4 + r;
                        e = (kk <= q0w + qf * 16 + l15) ? e : 0.0f;
                    }
                    psum[qf] += e;
                    pv[r] = e;
                }
                uint2 w;
                w.x = __builtin_bit_cast(u32, __builtin_amdgcn_cvt_pkrtz(pv[0], pv[1]));
                w.y = __builtin_bit_cast(u32, __builtin_amdgcn_cvt_pkrtz(pv[2], pv[3]));
                *(uint2*)(Pw + c * 16 + lg * 4) = w;
            }
        }
        f16x8 pa0[2], pa1[2];
#pragma unroll
        for (int qf = 0; qf < 2; qf++) {
            const u16* Pw = qf ? Pw1 : Pw0;
            pa0[qf] = *(const f16x8*)(Pw + lg * 8);
            pa1[qf] = *(const f16x8*)(Pw + 32 + lg * 8);
        }
#pragma unroll
        for (int dt = 0; dt < 4; dt++) {
            const u16* vp = Vs[bf] + (dt * 16 + l15) * 64;
            f16x8 vf0 = *(const f16x8*)(vp + swk0);
            f16x8 vf1 = *(const f16x8*)(vp + swk1);
#pragma unroll
            for (int qf = 0; qf < 2; qf++) {
                acc[qf][dt] =
                    __builtin_amdgcn_mfma_f32_16x16x32_f16(pa0[qf], vf0, acc[qf][dt], 0, 0, 0);
                acc[qf][dt] =
                    __builtin_amdgcn_mfma_f32_16x16x32_f16(pa1[qf], vf1, acc[qf][dt], 0, 0, 0);
            }
        }
    };

    stage(0, 0);
    int cur = 0;
    for (int s = 0; s < send; s += 64) {
        __syncthreads();
        stage(s + 64, cur ^ 1);
        body(s, cur, BoolTag<false>{});
        cur ^= 1;
    }
#pragma unroll 1
    for (int j = 0; j < 4; j++) {
        __syncthreads();
        if (j < 3) stage(send + 64 * (j + 1), cur ^ 1);
        if (wid >= 2 * j) body(send + 64 * j, cur, BoolTag<true>{});
        cur ^= 1;
    }

#pragma unroll
    for (int qf = 0; qf < 2; qf++) {
        psum[qf] += __shfl_xor(psum[qf], 16);
        psum[qf] += __shfl_xor(psum[qf], 32);
    }
#pragma unroll
    for (int qf = 0; qf < 2; qf++) {
        float inv = 1.0f / psum[qf];
#pragma unroll
        for (int r = 0; r < 4; r++) {
            float ir = __shfl(inv, lg * 4 + r);
            size_t row = (size_t)b * 2048 + q0w + qf * 16 + lg * 4 + r;
#pragma unroll
            for (int dt = 0; dt < 4; dt++)
                ctx[row * 1024 + h * 64 + dt * 16 + l15] = f2h_bits(acc[qf][dt][r] * ir);
        }
    }
}

// -------------------------------------------------------------- layer norm
__global__ __launch_bounds__(256) void ln_kernel(const float* __restrict__ y,
                                                 const float* __restrict__ g,
                                                 const float* __restrict__ bb,
                                                 float* __restrict__ out) {
    const int r = blockIdx.x, tid = threadIdx.x;
    float4 v = *(const float4*)(y + (size_t)r * 1024 + tid * 4);
    float s = v.x + v.y + v.z + v.w;
    float sq = v.x * v.x + v.y * v.y + v.z * v.z + v.w * v.w;
#pragma unroll
    for (int ofs = 1; ofs < 64; ofs <<= 1) {
        s += __shfl_xor(s, ofs);
        sq += __shfl_xor(sq, ofs);
    }
    __shared__ float as[4], aq[4];
    if ((tid & 63) == 0) { as[tid >> 6] = s; aq[tid >> 6] = sq; }
    __syncthreads();
    s = as[0] + as[1] + as[2] + as[3];
    sq = aq[0] + aq[1] + aq[2] + aq[3];
    float mu = s * (1.0f / 1024.0f);
    float var = sq * (1.0f / 1024.0f) - mu * mu;
    float rstd = rsqrtf(var + 1e-5f);
    float4 gv = *(const float4*)(g + tid * 4);
    float4 bv = *(const float4*)(bb + tid * 4);
    float4 o4;
    o4.x = (v.x - mu) * rstd * gv.x + bv.x;
    o4.y = (v.y - mu) * rstd * gv.y + bv.y;
    o4.z = (v.z - mu) * rstd * gv.z + bv.z;
    o4.w = (v.w - mu) * rstd * gv.w + bv.w;
    *(float4*)(out + (size_t)r * 1024 + tid * 4) = o4;
}

// ------------------------------------------------------------------ launch
extern "C" void kernel_launch(void* const* d_in, const int* in_sizes, int n_in,
                              void* d_out, int out_size, void* d_ws, size_t ws_size,
                              hipStream_t stream) {
    const float* x  = (const float*)d_in[0];
    const float* Wq = (const float*)d_in[1];
    const float* bq = (const float*)d_in[2];
    const float* Wk = (const float*)d_in[3];
    const float* bk = (const float*)d_in[4];
    const float* Wv = (const float*)d_in[5];
    const float* bv = (const float*)d_in[6];
    const float* Wo = (const float*)d_in[7];
    const float* bo = (const float*)d_in[8];
    const float* lg = (const float*)d_in[9];
    const float* lb = (const float*)d_in[10];
    float* out = (float*)d_out;

    char* ws = (char*)d_ws;
    u16* xb = (u16*)(ws + 0);
    u16* wt = (u16*)(ws + 16777216);
    u16* q  = (u16*)(ws + 25165824);
    u16* k  = (u16*)(ws + 41943040);
    u16* vt = (u16*)(ws + 75497472);
    u16* cx = (u16*)(ws + 92274688);
    float* y = (float*)(ws + 109051904);

    convert_kernel<<<5120, 256, 0, stream>>>(x, xb, Wq, Wk, Wv, Wo, wt);

    gemm256_kernel<0><<<768, 512, 0, stream>>>(xb, wt, bq, bk, bv, q, k, vt,
                                               nullptr, nullptr);
    attn_kernel<<<dim3(64, 8), 512, 0, stream>>>(q, k, vt, cx);
    gemm256_kernel<1><<<256, 512, 0, stream>>>(cx, wt + 3145728, bo, nullptr,
                                               nullptr, nullptr, nullptr, nullptr,
                                               y, x);
    ln_kernel<<<8192, 256, 0, stream>>>(y, lg, lb, out);
}

// Round 13
// 181.574 us; speedup vs baseline: 1.0826x; 1.0826x over previous
//
#include <hip/hip_runtime.h>

// Problem constants: B=4, T=2048, D=1024, H=16, DK=64, M = B*T = 8192.
// Workspace layout (bytes):
//   xb  @ 0         : x as fp16            (16 MB)
//   wt  @ 16 MB     : Wq,Wk,Wv,Wo transposed [N][K] fp16 (4 x 2 MB)
//   q   @ 24 MB     : Q (pre-scaled by log2e/8) [B*T, D] fp16 (16 MB)
//   k   @ 40 MB     : K  [B*T, D] fp16     (16 MB)
//   vt  @ 72 MB     : V^T [B*H][64][T] fp16(16 MB)  <- written by QKV epilogue
//   cx  @ 88 MB     : attention ctx fp16   (16 MB)
//   y   @ 104 MB    : pre-LN f32           (32 MB)

using u16 = unsigned short;
using u32 = unsigned int;
typedef _Float16 f16x8 __attribute__((ext_vector_type(8)));
typedef __fp16 h16x2 __attribute__((ext_vector_type(2)));   // cvt_pkrtz/fdot2 type
typedef float f32x4 __attribute__((ext_vector_type(4)));
typedef unsigned short u16x8 __attribute__((ext_vector_type(8)));

template <bool B> struct BoolTag { static constexpr bool v = B; };

__device__ inline u16 f2h_bits(float f) {
    _Float16 h = (_Float16)f;
    return __builtin_bit_cast(u16, h);
}

__device__ __forceinline__ void gload16(const void* g, void* l) {
    __builtin_amdgcn_global_load_lds(
        (const __attribute__((address_space(1))) void*)g,
        (__attribute__((address_space(3))) void*)l, 16, 0, 0);
}

// -------------------------- fused converts: x -> fp16, W^T x4 -> fp16
// blocks 0..4095: x;  blocks 4096..5119: weight tiles (z = wb>>8).
__global__ __launch_bounds__(256) void convert_kernel(
    const float* __restrict__ x, u16* __restrict__ xb,
    const float* __restrict__ W0, const float* __restrict__ W1,
    const float* __restrict__ W2, const float* __restrict__ W3,
    u16* __restrict__ Wt) {
    __shared__ float ts[64][68];
    const int bid = blockIdx.x, tid = threadIdx.x;
    if (bid < 4096) {
        size_t i = ((size_t)bid * 256 + tid) * 8;
        float4 a = *(const float4*)(x + i);
        float4 b = *(const float4*)(x + i + 4);
        u16x8 o;
        o[0] = f2h_bits(a.x); o[1] = f2h_bits(a.y); o[2] = f2h_bits(a.z); o[3] = f2h_bits(a.w);
        o[4] = f2h_bits(b.x); o[5] = f2h_bits(b.y); o[6] = f2h_bits(b.z); o[7] = f2h_bits(b.w);
        *(u16x8*)(xb + i) = o;
        return;
    }
    const int wb = bid - 4096;
    const int z = wb >> 8, rem = wb & 255;
    const float* W = z == 0 ? W0 : (z == 1 ? W1 : (z == 2 ? W2 : W3));
    u16* Wo = Wt + (size_t)z * 1048576;
    const int k0 = (rem >> 4) * 64, n0 = (rem & 15) * 64;
    const int rr = tid >> 3, c = tid & 7;
#pragma unroll
    for (int p = 0; p < 2; p++) {
        int k = p * 32 + rr;
        float4 u = *(const float4*)(W + (size_t)(k0 + k) * 1024 + n0 + c * 8);
        float4 w = *(const float4*)(W + (size_t)(k0 + k) * 1024 + n0 + c * 8 + 4);
        *(float4*)&ts[k][c * 8] = u;
        *(float4*)&ts[k][c * 8 + 4] = w;
    }
    __syncthreads();
#pragma unroll
    for (int p = 0; p < 2; p++) {
        int n = p * 32 + rr;
        u16 o[8];
#pragma unroll
        for (int j = 0; j < 8; j++) o[j] = f2h_bits(ts[c * 8 + j][n]);
        *(u16x8*)(Wo + (size_t)(n0 + n) * 1024 + k0 + c * 8) = *(u16x8*)o;
    }
}

// --------------------------------------------------------- 128x256 GEMM
// C[M,N] = A[M,1024] @ W (W as Wt[N][1024] fp16). BM=128, BN=256, BK=64.
// 512 threads = 8 waves (2M x 4N), per-wave 64x64. Triple-buffered LDS,
// m201-style phases, counted vmcnt(6) per K-tile.
// MODE 0: QKV fused (N=3072): Q/K fp16 out + bias (+log2e/8 scale on Q);
//         V blocks transpose in-LDS (stride 134) and write vt directly.
// MODE 1: Wo (N=1024), f32 out + bias + residual.
template <int MODE>
__global__ __launch_bounds__(512) void gemm256_kernel(
    const u16* __restrict__ A, const u16* __restrict__ Wt,
    const float* __restrict__ b0, const float* __restrict__ b1,
    const float* __restrict__ b2, u16* __restrict__ qo, u16* __restrict__ ko,
    u16* __restrict__ vt, float* __restrict__ outf,
    const float* __restrict__ xres) {
    constexpr int NBY = (MODE == 0) ? 12 : 4;
    __shared__ u16 As[3][128 * 64];
    __shared__ u16 Bs[3][256 * 64];

    const int bid = blockIdx.x;
    const int cpx = (MODE == 0) ? 96 : 32;        // gridDim/8, grid%8==0
    const int swz = (bid & 7) * cpx + (bid >> 3); // XCD-contiguous
    const int bx = swz / NBY, by = swz % NBY;
    const size_t row0 = (size_t)bx * 128;
    const size_t col0 = (size_t)by * 256;

    const int tid = threadIdx.x, lane = tid & 63;
    const int wid = tid >> 6, wm = wid >> 2, wn = wid & 3;
    const int l15 = lane & 15, lg = lane >> 4;
    const int rr = tid >> 3, c8 = tid & 7;
    const int scw = (c8 ^ (rr & 7)) * 8;          // pre-swizzled source chunk

    f32x4 acc[4][4] = {};

    auto stage_half = [&](int kt, u16* dA, u16* dB, int h) {
        const int k0 = kt * 64;
        if (h == 0) {
            gload16(A + (row0 + rr) * 1024 + k0 + scw, dA + tid * 8);
            gload16(Wt + (col0 + rr) * 1024 + k0 + scw, dB + tid * 8);
            gload16(Wt + (col0 + 64 + rr) * 1024 + k0 + scw, dB + (512 + tid) * 8);
        } else {
            gload16(A + (row0 + 64 + rr) * 1024 + k0 + scw, dA + (512 + tid) * 8);
            gload16(Wt + (col0 + 128 + rr) * 1024 + k0 + scw, dB + (1024 + tid) * 8);
            gload16(Wt + (col0 + 192 + rr) * 1024 + k0 + scw, dB + (1536 + tid) * 8);
        }
    };

    auto ldops = [&](const u16* bA, const u16* bB, int kcv, f16x8* Af, f16x8* Bf) {
        const int swo = ((kcv * 4 + lg) ^ (l15 & 7)) * 8;
#pragma unroll
        for (int n = 0; n < 4; n++)
            Bf[n] = *(const f16x8*)(bB + (wn * 64 + n * 16 + l15) * 64 + swo);
#pragma unroll
        for (int m = 0; m < 4; m++)
            Af[m] = *(const f16x8*)(bA + (wm * 64 + m * 16 + l15) * 64 + swo);
    };

    auto domfma = [&](const f16x8* Af, const f16x8* Bf) {
        __builtin_amdgcn_s_setprio(1);
#pragma unroll
        for (int m = 0; m < 4; m++)
#pragma unroll
            for (int n = 0; n < 4; n++)
                acc[m][n] = __builtin_amdgcn_mfma_f32_16x16x32_f16(
                    Af[m], Bf[n], acc[m][n], 0, 0, 0);
        __builtin_amdgcn_s_setprio(0);
    };

    u16 *pA = &As[0][0], *pnA = &As[1][0], *ppA = &As[2][0];
    u16 *pB = &Bs[0][0], *pnB = &Bs[1][0], *ppB = &Bs[2][0];

    stage_half(0, pA, pB, 0);
    stage_half(0, pA, pB, 1);
    stage_half(1, pnA, pnB, 0);
    stage_half(1, pnA, pnB, 1);
    asm volatile("s_waitcnt vmcnt(6)" ::: "memory");
    __builtin_amdgcn_sched_barrier(0);
    __builtin_amdgcn_s_barrier();

#pragma unroll 1
    for (int t = 0; t < 16; t++) {
        f16x8 af[4], bf[4];
        ldops(pA, pB, 0, af, bf);
        if (t < 14) stage_half(t + 2, ppA, ppB, 0);
        __builtin_amdgcn_sched_barrier(0);
        __builtin_amdgcn_s_barrier();
        asm volatile("s_waitcnt lgkmcnt(0)" ::: "memory");
        __builtin_amdgcn_sched_barrier(0);
        domfma(af, bf);
        __builtin_amdgcn_sched_barrier(0);
        __builtin_amdgcn_s_barrier();
        ldops(pA, pB, 1, af, bf);
        if (t < 14) stage_half(t + 2, ppA, ppB, 1);
        if (t < 14)       asm volatile("s_waitcnt vmcnt(6)" ::: "memory");
        else if (t == 14) asm volatile("s_waitcnt vmcnt(0)" ::: "memory");
        __builtin_amdgcn_sched_barrier(0);
        __builtin_amdgcn_s_barrier();
        asm volatile("s_waitcnt lgkmcnt(0)" ::: "memory");
        __builtin_amdgcn_sched_barrier(0);
        domfma(af, bf);
        __builtin_amdgcn_sched_barrier(0);
        if (t < 15) {
            __builtin_amdgcn_s_barrier();
            u16* tp;
            tp = pA; pA = pnA; pnA = ppA; ppA = tp;
            tp = pB; pB = pnB; pnB = ppB; ppB = tp;
        }
    }

    if (MODE == 0) {
        const int zsel = by >> 2;  // 0=Q, 1=K, 2=V
        if (zsel < 2) {
            u16* ob = zsel == 0 ? qo : ko;
            const float* bias = zsel == 0 ? b0 : b1;
            const float qs = zsel == 0 ? 0.18033688f : 1.0f;  // log2(e)/8 on Q
#pragma unroll
            for (int m = 0; m < 4; m++) {
#pragma unroll
                for (int n = 0; n < 4; n++) {
                    size_t col = col0 + wn * 64 + n * 16 + l15;
                    size_t colz = col & 1023;
                    float bb = bias[colz];
#pragma unroll
                    for (int r = 0; r < 4; r++) {
                        size_t row = row0 + wm * 64 + m * 16 + lg * 4 + r;
                        ob[row * 1024 + colz] = f2h_bits((acc[m][n][r] + bb) * qs);
                    }
                }
            }
        } else {
            // V: bias + in-LDS transpose -> vt[(b*16+h)*64+d][t]
            u16* TL = &Bs[0][0];  // [256][134] u16 = 68608 B (Bs is 98304 B)
            __syncthreads();
#pragma unroll
            for (int m = 0; m < 4; m++) {
#pragma unroll
                for (int n = 0; n < 4; n++) {
                    int cl = wn * 64 + n * 16 + l15;
                    float bb = b2[(col0 & 1023) + cl];
#pragma unroll
                    for (int r = 0; r < 4; r++) {
                        int rl = wm * 64 + m * 16 + lg * 4 + r;
                        TL[cl * 134 + rl] = f2h_bits(acc[m][n][r] + bb);
                    }
                }
            }
            __syncthreads();
            const int vrl = tid >> 1, th = tid & 1;
            size_t vrow = (row0 >> 11) * 1024 + (col0 & 1023) + vrl;
            const int t0loc = (int)(row0 & 2047) + th * 64;
#pragma unroll
            for (int j = 0; j < 8; j++)
                *(u16x8*)(vt + vrow * 2048 + t0loc + j * 8) =
                    *(const u16x8*)(TL + vrl * 134 + th * 64 + j * 8);
        }
    } else {
#pragma unroll
        for (int m = 0; m < 4; m++) {
#pragma unroll
            for (int n = 0; n < 4; n++) {
                size_t col = col0 + wn * 64 + n * 16 + l15;
                float bb = b0[col];
#pragma unroll
                for (int r = 0; r < 4; r++) {
                    size_t row = row0 + wm * 64 + m * 16 + lg * 4 + r;
                    size_t idx = row * 1024 + col;
                    outf[idx] = acc[m][n][r] + bb + xres[idx];
                }
            }
        }
    }
}

// ------------------------------------------------------------- attention v8
// 8 waves x 32 q = 256 q/block, KV steps of 64, grid (64 bh, 8 qb big-first)
// = 512 blocks, 2 blocks/CU (all co-resident). exp2-direct softmax with NO
// clamp (cvt_pkrtz saturates; PV and psum use the same saturated P), psum
// via fdot2 on the packed fp16 P pairs (16 ops vs 32 adds). Swapped QK^T
// (mfma(K,Q)), packed P through padded [16][72] per-wave-qf P-LDS.
__global__ __launch_bounds__(512) void attn_kernel(const u16* __restrict__ Q,
                                                   const u16* __restrict__ Kb,
                                                   const u16* __restrict__ Vt,
                                                   u16* __restrict__ ctx) {
    __shared__ u16 Ks[2][64 * 64];
    __shared__ u16 Vs[2][64 * 64];
    __shared__ u16 Ps[8][2][16][72];

    const int bh = blockIdx.x;
    const int b = bh >> 4, h = bh & 15;
    const int qb = 7 - (int)blockIdx.y;  // big blocks dispatch first
    const int tid = threadIdx.x, lane = tid & 63, wid = tid >> 6;
    const int l15 = lane & 15, lg = lane >> 4;
    const int q0w = qb * 256 + wid * 32;
    const int send = qb * 256;

    const int rr = tid >> 3, c8 = tid & 7;
    const int scw = (c8 ^ (rr & 7)) * 8;
    const size_t kbase = ((size_t)b * 2048) * 1024 + h * 64 + scw;
    const size_t vbase = ((size_t)bh * 64 + rr) * 2048 + scw;

    f16x8 qv[2][2];
#pragma unroll
    for (int qf = 0; qf < 2; qf++) {
        size_t qoff = ((size_t)b * 2048 + q0w + qf * 16 + l15) * 1024 + h * 64 + lg * 8;
        qv[qf][0] = *(const f16x8*)(Q + qoff);
        qv[qf][1] = *(const f16x8*)(Q + qoff + 32);
    }

    const int swk0 = (lg ^ (l15 & 7)) * 8;
    const int swk1 = ((4 + lg) ^ (l15 & 7)) * 8;
    u16* Pw0 = &Ps[wid][0][0][0] + l15 * 72;
    u16* Pw1 = &Ps[wid][1][0][0] + l15 * 72;

    const h16x2 one2 = {(__fp16)1.0f, (__fp16)1.0f};

    f32x4 acc[2][4] = {};
    float psum[2] = {0.0f, 0.0f};

    auto stage = [&](int s, int bf) {
        gload16(Kb + kbase + (size_t)(s + rr) * 1024, Ks[bf] + tid * 8);
        gload16(Vt + vbase + s, Vs[bf] + tid * 8);
    };

    auto body = [&](int s, int bf, auto maskc) {
        constexpr bool MASK = decltype(maskc)::v;
#pragma unroll
        for (int c = 0; c < 4; c++) {
            const u16* kp = Ks[bf] + (c * 16 + l15) * 64;
            f16x8 kf0 = *(const f16x8*)(kp + swk0);
            f16x8 kf1 = *(const f16x8*)(kp + swk1);
#pragma unroll
            for (int qf = 0; qf < 2; qf++) {
                f32x4 z = {};
                z = __builtin_amdgcn_mfma_f32_16x16x32_f16(kf0, qv[qf][0], z, 0, 0, 0);
                z = __builtin_amdgcn_mfma_f32_16x16x32_f16(kf1, qv[qf][1], z, 0, 0, 0);
                float p0 = __builtin_amdgcn_exp2f(z[0]);
                float p1 = __builtin_amdgcn_exp2f(z[1]);
                float p2 = __builtin_amdgcn_exp2f(z[2]);
                float p3 = __builtin_amdgcn_exp2f(z[3]);
                if (MASK) {
                    int kk = s + c * 16 + lg * 4;
                    int qq = q0w + qf * 16 + l15;
                    p0 = (kk + 0 <= qq) ? p0 : 0.0f;
                    p1 = (kk + 1 <= qq) ? p1 : 0.0f;
                    p2 = (kk + 2 <= qq) ? p2 : 0.0f;
                    p3 = (kk + 3 <= qq) ? p3 : 0.0f;
                }
                h16x2 w0 = __builtin_amdgcn_cvt_pkrtz(p0, p1);
                h16x2 w1 = __builtin_amdgcn_cvt_pkrtz(p2, p3);
                psum[qf] = __builtin_amdgcn_fdot2(w0, one2, psum[qf], false);
                psum[qf] = __builtin_amdgcn_fdot2(w1, one2, psum[qf], false);
                uint2 w;
                w.x = __builtin_bit_cast(u32, w0);
                w.y = __builtin_bit_cast(u32, w1);
                *(uint2*)((qf ? Pw1 : Pw0) + c * 16 + lg * 4) = w;
            }
        }
        f16x8 pa0[2], pa1[2];
#pragma unroll
        for (int qf = 0; qf < 2; qf++) {
            const u16* Pw = qf ? Pw1 : Pw0;
            pa0[qf] = *(const f16x8*)(Pw + lg * 8);
            pa1[qf] = *(const f16x8*)(Pw + 32 + lg * 8);
        }
#pragma unroll
        for (int dt = 0; dt < 4; dt++) {
            const u16* vp = Vs[bf] + (dt * 16 + l15) * 64;
            f16x8 vf0 = *(const f16x8*)(vp + swk0);
            f16x8 vf1 = *(const f16x8*)(vp + swk1);
#pragma unroll
            for (int qf = 0; qf < 2; qf++) {
                acc[qf][dt] =
                    __builtin_amdgcn_mfma_f32_16x16x32_f16(pa0[qf], vf0, acc[qf][dt], 0, 0, 0);
                acc[qf][dt] =
                    __builtin_amdgcn_mfma_f32_16x16x32_f16(pa1[qf], vf1, acc[qf][dt], 0, 0, 0);
            }
        }
    };

    stage(0, 0);
    int cur = 0;
    for (int s = 0; s < send; s += 64) {
        __syncthreads();
        stage(s + 64, cur ^ 1);
        body(s, cur, BoolTag<false>{});
        cur ^= 1;
    }
#pragma unroll 1
    for (int j = 0; j < 4; j++) {
        __syncthreads();
        if (j < 3) stage(send + 64 * (j + 1), cur ^ 1);
        if (wid >= 2 * j) body(send + 64 * j, cur, BoolTag<true>{});
        cur ^= 1;
    }

#pragma unroll
    for (int qf = 0; qf < 2; qf++) {
        psum[qf] += __shfl_xor(psum[qf], 16);
        psum[qf] += __shfl_xor(psum[qf], 32);
    }
#pragma unroll
    for (int qf = 0; qf < 2; qf++) {
        float inv = 1.0f / psum[qf];
#pragma unroll
        for (int r = 0; r < 4; r++) {
            float ir = __shfl(inv, lg * 4 + r);
            size_t row = (size_t)b * 2048 + q0w + qf * 16 + lg * 4 + r;
#pragma unroll
            for (int dt = 0; dt < 4; dt++)
                ctx[row * 1024 + h * 64 + dt * 16 + l15] = f2h_bits(acc[qf][dt][r] * ir);
        }
    }
}

// -------------------------------------------------------------- layer norm
__global__ __launch_bounds__(256) void ln_kernel(const float* __restrict__ y,
                                                 const float* __restrict__ g,
                                                 const float* __restrict__ bb,
                                                 float* __restrict__ out) {
    const int r = blockIdx.x, tid = threadIdx.x;
    float4 v = *(const float4*)(y + (size_t)r * 1024 + tid * 4);
    float s = v.x + v.y + v.z + v.w;
    float sq = v.x * v.x + v.y * v.y + v.z * v.z + v.w * v.w;
#pragma unroll
    for (int ofs = 1; ofs < 64; ofs <<= 1) {
        s += __shfl_xor(s, ofs);
        sq += __shfl_xor(sq, ofs);
    }
    __shared__ float as[4], aq[4];
    if ((tid & 63) == 0) { as[tid >> 6] = s; aq[tid >> 6] = sq; }
    __syncthreads();
    s = as[0] + as[1] + as[2] + as[3];
    sq = aq[0] + aq[1] + aq[2] + aq[3];
    float mu = s * (1.0f / 1024.0f);
    float var = sq * (1.0f / 1024.0f) - mu * mu;
    float rstd = rsqrtf(var + 1e-5f);
    float4 gv = *(const float4*)(g + tid * 4);
    float4 bv = *(const float4*)(bb + tid * 4);
    float4 o4;
    o4.x = (v.x - mu) * rstd * gv.x + bv.x;
    o4.y = (v.y - mu) * rstd * gv.y + bv.y;
    o4.z = (v.z - mu) * rstd * gv.z + bv.z;
    o4.w = (v.w - mu) * rstd * gv.w + bv.w;
    *(float4*)(out + (size_t)r * 1024 + tid * 4) = o4;
}

// ------------------------------------------------------------------ launch
extern "C" void kernel_launch(void* const* d_in, const int* in_sizes, int n_in,
                              void* d_out, int out_size, void* d_ws, size_t ws_size,
                              hipStream_t stream) {
    const float* x  = (const float*)d_in[0];
    const float* Wq = (const float*)d_in[1];
    const float* bq = (const float*)d_in[2];
    const float* Wk = (const float*)d_in[3];
    const float* bk = (const float*)d_in[4];
    const float* Wv = (const float*)d_in[5];
    const float* bv = (const float*)d_in[6];
    const float* Wo = (const float*)d_in[7];
    const float* bo = (const float*)d_in[8];
    const float* lg = (const float*)d_in[9];
    const float* lb = (const float*)d_in[10];
    float* out = (float*)d_out;

    char* ws = (char*)d_ws;
    u16* xb = (u16*)(ws + 0);
    u16* wt = (u16*)(ws + 16777216);
    u16* q  = (u16*)(ws + 25165824);
    u16* k  = (u16*)(ws + 41943040);
    u16* vt = (u16*)(ws + 75497472);
    u16* cx = (u16*)(ws + 92274688);
    float* y = (float*)(ws + 109051904);

    convert_kernel<<<5120, 256, 0, stream>>>(x, xb, Wq, Wk, Wv, Wo, wt);

    gemm256_kernel<0><<<768, 512, 0, stream>>>(xb, wt, bq, bk, bv, q, k, vt,
                                               nullptr, nullptr);
    attn_kernel<<<dim3(64, 8), 512, 0, stream>>>(q, k, vt, cx);
    gemm256_kernel<1><<<256, 512, 0, stream>>>(cx, wt + 3145728, bo, nullptr,
                                               nullptr, nullptr, nullptr, nullptr,
                                               y, x);
    ln_kernel<<<8192, 256, 0, stream>>>(y, lg, lb, out);
}

// Round 14
// 176.823 us; speedup vs baseline: 1.1117x; 1.0269x over previous
//
#include <hip/hip_runtime.h>

// Problem constants: B=4, T=2048, D=1024, H=16, DK=64, M = B*T = 8192.
// Workspace layout (bytes):
//   xb  @ 0         : x as fp16            (16 MB)   (also residual source)
//   wt  @ 16 MB     : Wq,Wk,Wv,Wo transposed [N][K] fp16 (4 x 2 MB)
//   q   @ 24 MB     : Q (pre-scaled by log2e/8) [B*T, D] fp16 (16 MB)
//   k   @ 40 MB     : K  [B*T, D] fp16     (16 MB)
//   vt  @ 72 MB     : V^T [B*H][64][T] fp16(16 MB)  <- written by QKV epilogue
//   cx  @ 88 MB     : attention ctx fp16   (16 MB)
//   y   @ 104 MB    : pre-LN fp16          (16 MB)

using u16 = unsigned short;
using u32 = unsigned int;
typedef _Float16 f16x8 __attribute__((ext_vector_type(8)));
typedef __fp16 h16x2 __attribute__((ext_vector_type(2)));   // cvt_pkrtz/fdot2 type
typedef float f32x4 __attribute__((ext_vector_type(4)));
typedef unsigned short u16x8 __attribute__((ext_vector_type(8)));
typedef unsigned short u16x4 __attribute__((ext_vector_type(4)));

template <bool B> struct BoolTag { static constexpr bool v = B; };

__device__ inline u16 f2h_bits(float f) {
    _Float16 h = (_Float16)f;
    return __builtin_bit_cast(u16, h);
}
__device__ inline float h2f(u16 u) {
    return (float)__builtin_bit_cast(_Float16, u);
}

__device__ __forceinline__ void gload16(const void* g, void* l) {
    __builtin_amdgcn_global_load_lds(
        (const __attribute__((address_space(1))) void*)g,
        (__attribute__((address_space(3))) void*)l, 16, 0, 0);
}

// -------------------------- fused converts: x -> fp16, W^T x4 -> fp16
// blocks 0..4095: x;  blocks 4096..5119: weight tiles (z = wb>>8).
__global__ __launch_bounds__(256) void convert_kernel(
    const float* __restrict__ x, u16* __restrict__ xb,
    const float* __restrict__ W0, const float* __restrict__ W1,
    const float* __restrict__ W2, const float* __restrict__ W3,
    u16* __restrict__ Wt) {
    __shared__ float ts[64][68];
    const int bid = blockIdx.x, tid = threadIdx.x;
    if (bid < 4096) {
        size_t i = ((size_t)bid * 256 + tid) * 8;
        float4 a = *(const float4*)(x + i);
        float4 b = *(const float4*)(x + i + 4);
        u16x8 o;
        o[0] = f2h_bits(a.x); o[1] = f2h_bits(a.y); o[2] = f2h_bits(a.z); o[3] = f2h_bits(a.w);
        o[4] = f2h_bits(b.x); o[5] = f2h_bits(b.y); o[6] = f2h_bits(b.z); o[7] = f2h_bits(b.w);
        *(u16x8*)(xb + i) = o;
        return;
    }
    const int wb = bid - 4096;
    const int z = wb >> 8, rem = wb & 255;
    const float* W = z == 0 ? W0 : (z == 1 ? W1 : (z == 2 ? W2 : W3));
    u16* Wo = Wt + (size_t)z * 1048576;
    const int k0 = (rem >> 4) * 64, n0 = (rem & 15) * 64;
    const int rr = tid >> 3, c = tid & 7;
#pragma unroll
    for (int p = 0; p < 2; p++) {
        int k = p * 32 + rr;
        float4 u = *(const float4*)(W + (size_t)(k0 + k) * 1024 + n0 + c * 8);
        float4 w = *(const float4*)(W + (size_t)(k0 + k) * 1024 + n0 + c * 8 + 4);
        *(float4*)&ts[k][c * 8] = u;
        *(float4*)&ts[k][c * 8 + 4] = w;
    }
    __syncthreads();
#pragma unroll
    for (int p = 0; p < 2; p++) {
        int n = p * 32 + rr;
        u16 o[8];
#pragma unroll
        for (int j = 0; j < 8; j++) o[j] = f2h_bits(ts[c * 8 + j][n]);
        *(u16x8*)(Wo + (size_t)(n0 + n) * 1024 + k0 + c * 8) = *(u16x8*)o;
    }
}

// --------------------------------------------------------- 128x256 GEMM
// C[M,N] = A[M,1024] @ W (W as Wt[N][1024] fp16). BM=128, BN=256, BK=64.
// 512 threads = 8 waves (2M x 4N), per-wave 64x64. Triple-buffered LDS,
// m201-style phases, counted vmcnt(6) per K-tile.
// MODE 0: QKV fused (N=3072): Q/K fp16 out + bias (+log2e/8 scale on Q);
//         V blocks transpose in-LDS (stride 134) and write vt directly.
// MODE 1: Wo: y16 = fp16(acc + bias + residual_fp16); qo=y16 out, ko=xb.
template <int MODE>
__global__ __launch_bounds__(512) void gemm256_kernel(
    const u16* __restrict__ A, const u16* __restrict__ Wt,
    const float* __restrict__ b0, const float* __restrict__ b1,
    const float* __restrict__ b2, u16* __restrict__ qo, u16* __restrict__ ko,
    u16* __restrict__ vt) {
    constexpr int NBY = (MODE == 0) ? 12 : 4;
    __shared__ u16 As[3][128 * 64];
    __shared__ u16 Bs[3][256 * 64];

    const int bid = blockIdx.x;
    const int cpx = (MODE == 0) ? 96 : 32;        // gridDim/8, grid%8==0
    const int swz = (bid & 7) * cpx + (bid >> 3); // XCD-contiguous
    const int bx = swz / NBY, by = swz % NBY;
    const size_t row0 = (size_t)bx * 128;
    const size_t col0 = (size_t)by * 256;

    const int tid = threadIdx.x, lane = tid & 63;
    const int wid = tid >> 6, wm = wid >> 2, wn = wid & 3;
    const int l15 = lane & 15, lg = lane >> 4;
    const int rr = tid >> 3, c8 = tid & 7;
    const int scw = (c8 ^ (rr & 7)) * 8;          // pre-swizzled source chunk

    f32x4 acc[4][4] = {};

    auto stage_half = [&](int kt, u16* dA, u16* dB, int h) {
        const int k0 = kt * 64;
        if (h == 0) {
            gload16(A + (row0 + rr) * 1024 + k0 + scw, dA + tid * 8);
            gload16(Wt + (col0 + rr) * 1024 + k0 + scw, dB + tid * 8);
            gload16(Wt + (col0 + 64 + rr) * 1024 + k0 + scw, dB + (512 + tid) * 8);
        } else {
            gload16(A + (row0 + 64 + rr) * 1024 + k0 + scw, dA + (512 + tid) * 8);
            gload16(Wt + (col0 + 128 + rr) * 1024 + k0 + scw, dB + (1024 + tid) * 8);
            gload16(Wt + (col0 + 192 + rr) * 1024 + k0 + scw, dB + (1536 + tid) * 8);
        }
    };

    auto ldops = [&](const u16* bA, const u16* bB, int kcv, f16x8* Af, f16x8* Bf) {
        const int swo = ((kcv * 4 + lg) ^ (l15 & 7)) * 8;
#pragma unroll
        for (int n = 0; n < 4; n++)
            Bf[n] = *(const f16x8*)(bB + (wn * 64 + n * 16 + l15) * 64 + swo);
#pragma unroll
        for (int m = 0; m < 4; m++)
            Af[m] = *(const f16x8*)(bA + (wm * 64 + m * 16 + l15) * 64 + swo);
    };

    auto domfma = [&](const f16x8* Af, const f16x8* Bf) {
        __builtin_amdgcn_s_setprio(1);
#pragma unroll
        for (int m = 0; m < 4; m++)
#pragma unroll
            for (int n = 0; n < 4; n++)
                acc[m][n] = __builtin_amdgcn_mfma_f32_16x16x32_f16(
                    Af[m], Bf[n], acc[m][n], 0, 0, 0);
        __builtin_amdgcn_s_setprio(0);
    };

    u16 *pA = &As[0][0], *pnA = &As[1][0], *ppA = &As[2][0];
    u16 *pB = &Bs[0][0], *pnB = &Bs[1][0], *ppB = &Bs[2][0];

    stage_half(0, pA, pB, 0);
    stage_half(0, pA, pB, 1);
    stage_half(1, pnA, pnB, 0);
    stage_half(1, pnA, pnB, 1);
    asm volatile("s_waitcnt vmcnt(6)" ::: "memory");
    __builtin_amdgcn_sched_barrier(0);
    __builtin_amdgcn_s_barrier();

#pragma unroll 1
    for (int t = 0; t < 16; t++) {
        f16x8 af[4], bf[4];
        ldops(pA, pB, 0, af, bf);
        if (t < 14) stage_half(t + 2, ppA, ppB, 0);
        __builtin_amdgcn_sched_barrier(0);
        __builtin_amdgcn_s_barrier();
        asm volatile("s_waitcnt lgkmcnt(0)" ::: "memory");
        __builtin_amdgcn_sched_barrier(0);
        domfma(af, bf);
        __builtin_amdgcn_sched_barrier(0);
        __builtin_amdgcn_s_barrier();
        ldops(pA, pB, 1, af, bf);
        if (t < 14) stage_half(t + 2, ppA, ppB, 1);
        if (t < 14)       asm volatile("s_waitcnt vmcnt(6)" ::: "memory");
        else if (t == 14) asm volatile("s_waitcnt vmcnt(0)" ::: "memory");
        __builtin_amdgcn_sched_barrier(0);
        __builtin_amdgcn_s_barrier();
        asm volatile("s_waitcnt lgkmcnt(0)" ::: "memory");
        __builtin_amdgcn_sched_barrier(0);
        domfma(af, bf);
        __builtin_amdgcn_sched_barrier(0);
        if (t < 15) {
            __builtin_amdgcn_s_barrier();
            u16* tp;
            tp = pA; pA = pnA; pnA = ppA; ppA = tp;
            tp = pB; pB = pnB; pnB = ppB; ppB = tp;
        }
    }

    if (MODE == 0) {
        const int zsel = by >> 2;  // 0=Q, 1=K, 2=V
        if (zsel < 2) {
            u16* ob = zsel == 0 ? qo : ko;
            const float* bias = zsel == 0 ? b0 : b1;
            const float qs = zsel == 0 ? 0.18033688f : 1.0f;  // log2(e)/8 on Q
#pragma unroll
            for (int m = 0; m < 4; m++) {
#pragma unroll
                for (int n = 0; n < 4; n++) {
                    size_t col = col0 + wn * 64 + n * 16 + l15;
                    size_t colz = col & 1023;
                    float bb = bias[colz];
#pragma unroll
                    for (int r = 0; r < 4; r++) {
                        size_t row = row0 + wm * 64 + m * 16 + lg * 4 + r;
                        ob[row * 1024 + colz] = f2h_bits((acc[m][n][r] + bb) * qs);
                    }
                }
            }
        } else {
            // V: bias + in-LDS transpose -> vt[(b*16+h)*64+d][t]
            u16* TL = &Bs[0][0];  // [256][134] u16 = 68608 B (Bs is 98304 B)
            __syncthreads();
#pragma unroll
            for (int m = 0; m < 4; m++) {
#pragma unroll
                for (int n = 0; n < 4; n++) {
                    int cl = wn * 64 + n * 16 + l15;
                    float bb = b2[(col0 & 1023) + cl];
#pragma unroll
                    for (int r = 0; r < 4; r++) {
                        int rl = wm * 64 + m * 16 + lg * 4 + r;
                        TL[cl * 134 + rl] = f2h_bits(acc[m][n][r] + bb);
                    }
                }
            }
            __syncthreads();
            const int vrl = tid >> 1, th = tid & 1;
            size_t vrow = (row0 >> 11) * 1024 + (col0 & 1023) + vrl;
            const int t0loc = (int)(row0 & 2047) + th * 64;
#pragma unroll
            for (int j = 0; j < 8; j++)
                *(u16x8*)(vt + vrow * 2048 + t0loc + j * 8) =
                    *(const u16x8*)(TL + vrl * 134 + th * 64 + j * 8);
        }
    } else {
        // Wo: y16 = fp16(acc + bias + fp16 residual from xb)
        u16* yo = qo;
        const u16* xres = ko;
#pragma unroll
        for (int m = 0; m < 4; m++) {
#pragma unroll
            for (int n = 0; n < 4; n++) {
                size_t col = col0 + wn * 64 + n * 16 + l15;
                float bb = b0[col];
#pragma unroll
                for (int r = 0; r < 4; r++) {
                    size_t row = row0 + wm * 64 + m * 16 + lg * 4 + r;
                    size_t idx = row * 1024 + col;
                    yo[idx] = f2h_bits(acc[m][n][r] + bb + h2f(xres[idx]));
                }
            }
        }
    }
}

// ------------------------------------------------------------- attention v8
// 8 waves x 32 q = 256 q/block, KV steps of 64, grid (64 bh, 8 qb big-first)
// = 512 blocks, 2 blocks/CU (all co-resident). exp2-direct softmax with NO
// clamp (cvt_pkrtz saturates; PV and psum use the same saturated P), psum
// via fdot2 on the packed fp16 P pairs. Swapped QK^T (mfma(K,Q)), packed P
// through padded [16][72] per-wave-qf P-LDS.
__global__ __launch_bounds__(512) void attn_kernel(const u16* __restrict__ Q,
                                                   const u16* __restrict__ Kb,
                                                   const u16* __restrict__ Vt,
                                                   u16* __restrict__ ctx) {
    __shared__ u16 Ks[2][64 * 64];
    __shared__ u16 Vs[2][64 * 64];
    __shared__ u16 Ps[8][2][16][72];

    const int bh = blockIdx.x;
    const int b = bh >> 4, h = bh & 15;
    const int qb = 7 - (int)blockIdx.y;  // big blocks dispatch first
    const int tid = threadIdx.x, lane = tid & 63, wid = tid >> 6;
    const int l15 = lane & 15, lg = lane >> 4;
    const int q0w = qb * 256 + wid * 32;
    const int send = qb * 256;

    const int rr = tid >> 3, c8 = tid & 7;
    const int scw = (c8 ^ (rr & 7)) * 8;
    const size_t kbase = ((size_t)b * 2048) * 1024 + h * 64 + scw;
    const size_t vbase = ((size_t)bh * 64 + rr) * 2048 + scw;

    f16x8 qv[2][2];
#pragma unroll
    for (int qf = 0; qf < 2; qf++) {
        size_t qoff = ((size_t)b * 2048 + q0w + qf * 16 + l15) * 1024 + h * 64 + lg * 8;
        qv[qf][0] = *(const f16x8*)(Q + qoff);
        qv[qf][1] = *(const f16x8*)(Q + qoff + 32);
    }

    const int swk0 = (lg ^ (l15 & 7)) * 8;
    const int swk1 = ((4 + lg) ^ (l15 & 7)) * 8;
    u16* Pw0 = &Ps[wid][0][0][0] + l15 * 72;
    u16* Pw1 = &Ps[wid][1][0][0] + l15 * 72;

    const h16x2 one2 = {(__fp16)1.0f, (__fp16)1.0f};

    f32x4 acc[2][4] = {};
    float psum[2] = {0.0f, 0.0f};

    auto stage = [&](int s, int bf) {
        gload16(Kb + kbase + (size_t)(s + rr) * 1024, Ks[bf] + tid * 8);
        gload16(Vt + vbase + s, Vs[bf] + tid * 8);
    };

    auto body = [&](int s, int bf, auto maskc) {
        constexpr bool MASK = decltype(maskc)::v;
#pragma unroll
        for (int c = 0; c < 4; c++) {
            const u16* kp = Ks[bf] + (c * 16 + l15) * 64;
            f16x8 kf0 = *(const f16x8*)(kp + swk0);
            f16x8 kf1 = *(const f16x8*)(kp + swk1);
#pragma unroll
            for (int qf = 0; qf < 2; qf++) {
                f32x4 z = {};
                z = __builtin_amdgcn_mfma_f32_16x16x32_f16(kf0, qv[qf][0], z, 0, 0, 0);
                z = __builtin_amdgcn_mfma_f32_16x16x32_f16(kf1, qv[qf][1], z, 0, 0, 0);
                float p0 = __builtin_amdgcn_exp2f(z[0]);
                float p1 = __builtin_amdgcn_exp2f(z[1]);
                float p2 = __builtin_amdgcn_exp2f(z[2]);
                float p3 = __builtin_amdgcn_exp2f(z[3]);
                if (MASK) {
                    int kk = s + c * 16 + lg * 4;
                    int qq = q0w + qf * 16 + l15;
                    p0 = (kk + 0 <= qq) ? p0 : 0.0f;
                    p1 = (kk + 1 <= qq) ? p1 : 0.0f;
                    p2 = (kk + 2 <= qq) ? p2 : 0.0f;
                    p3 = (kk + 3 <= qq) ? p3 : 0.0f;
                }
                h16x2 w0 = __builtin_amdgcn_cvt_pkrtz(p0, p1);
                h16x2 w1 = __builtin_amdgcn_cvt_pkrtz(p2, p3);
                psum[qf] = __builtin_amdgcn_fdot2(w0, one2, psum[qf], false);
                psum[qf] = __builtin_amdgcn_fdot2(w1, one2, psum[qf], false);
                uint2 w;
                w.x = __builtin_bit_cast(u32, w0);
                w.y = __builtin_bit_cast(u32, w1);
                *(uint2*)((qf ? Pw1 : Pw0) + c * 16 + lg * 4) = w;
            }
        }
        f16x8 pa0[2], pa1[2];
#pragma unroll
        for (int qf = 0; qf < 2; qf++) {
            const u16* Pw = qf ? Pw1 : Pw0;
            pa0[qf] = *(const f16x8*)(Pw + lg * 8);
            pa1[qf] = *(const f16x8*)(Pw + 32 + lg * 8);
        }
#pragma unroll
        for (int dt = 0; dt < 4; dt++) {
            const u16* vp = Vs[bf] + (dt * 16 + l15) * 64;
            f16x8 vf0 = *(const f16x8*)(vp + swk0);
            f16x8 vf1 = *(const f16x8*)(vp + swk1);
#pragma unroll
            for (int qf = 0; qf < 2; qf++) {
                acc[qf][dt] =
                    __builtin_amdgcn_mfma_f32_16x16x32_f16(pa0[qf], vf0, acc[qf][dt], 0, 0, 0);
                acc[qf][dt] =
                    __builtin_amdgcn_mfma_f32_16x16x32_f16(pa1[qf], vf1, acc[qf][dt], 0, 0, 0);
            }
        }
    };

    stage(0, 0);
    int cur = 0;
    for (int s = 0; s < send; s += 64) {
        __syncthreads();
        stage(s + 64, cur ^ 1);
        body(s, cur, BoolTag<false>{});
        cur ^= 1;
    }
#pragma unroll 1
    for (int j = 0; j < 4; j++) {
        __syncthreads();
        if (j < 3) stage(send + 64 * (j + 1), cur ^ 1);
        if (wid >= 2 * j) body(send + 64 * j, cur, BoolTag<true>{});
        cur ^= 1;
    }

#pragma unroll
    for (int qf = 0; qf < 2; qf++) {
        psum[qf] += __shfl_xor(psum[qf], 16);
        psum[qf] += __shfl_xor(psum[qf], 32);
    }
#pragma unroll
    for (int qf = 0; qf < 2; qf++) {
        float inv = 1.0f / psum[qf];
#pragma unroll
        for (int r = 0; r < 4; r++) {
            float ir = __shfl(inv, lg * 4 + r);
            size_t row = (size_t)b * 2048 + q0w + qf * 16 + lg * 4 + r;
#pragma unroll
            for (int dt = 0; dt < 4; dt++)
                ctx[row * 1024 + h * 64 + dt * 16 + l15] = f2h_bits(acc[qf][dt][r] * ir);
        }
    }
}

// -------------------------------------------------------------- layer norm
// y in fp16 (16 MB read vs 32), out f32.
__global__ __launch_bounds__(256) void ln_kernel(const u16* __restrict__ y,
                                                 const float* __restrict__ g,
                                                 const float* __restrict__ bb,
                                                 float* __restrict__ out) {
    const int r = blockIdx.x, tid = threadIdx.x;
    u16x4 v4 = *(const u16x4*)(y + (size_t)r * 1024 + tid * 4);
    float vx = h2f(v4[0]), vy = h2f(v4[1]), vz = h2f(v4[2]), vw = h2f(v4[3]);
    float s = vx + vy + vz + vw;
    float sq = vx * vx + vy * vy + vz * vz + vw * vw;
#pragma unroll
    for (int ofs = 1; ofs < 64; ofs <<= 1) {
        s += __shfl_xor(s, ofs);
        sq += __shfl_xor(sq, ofs);
    }
    __shared__ float as[4], aq[4];
    if ((tid & 63) == 0) { as[tid >> 6] = s; aq[tid >> 6] = sq; }
    __syncthreads();
    s = as[0] + as[1] + as[2] + as[3];
    sq = aq[0] + aq[1] + aq[2] + aq[3];
    float mu = s * (1.0f / 1024.0f);
    float var = sq * (1.0f / 1024.0f) - mu * mu;
    float rstd = rsqrtf(var + 1e-5f);
    float4 gv = *(const float4*)(g + tid * 4);
    float4 bv = *(const float4*)(bb + tid * 4);
    float4 o4;
    o4.x = (vx - mu) * rstd * gv.x + bv.x;
    o4.y = (vy - mu) * rstd * gv.y + bv.y;
    o4.z = (vz - mu) * rstd * gv.z + bv.z;
    o4.w = (vw - mu) * rstd * gv.w + bv.w;
    *(float4*)(out + (size_t)r * 1024 + tid * 4) = o4;
}

// ------------------------------------------------------------------ launch
extern "C" void kernel_launch(void* const* d_in, const int* in_sizes, int n_in,
                              void* d_out, int out_size, void* d_ws, size_t ws_size,
                              hipStream_t stream) {
    const float* x  = (const float*)d_in[0];
    const float* Wq = (const float*)d_in[1];
    const float* bq = (const float*)d_in[2];
    const float* Wk = (const float*)d_in[3];
    const float* bk = (const float*)d_in[4];
    const float* Wv = (const float*)d_in[5];
    const float* bv = (const float*)d_in[6];
    const float* Wo = (const float*)d_in[7];
    const float* bo = (const float*)d_in[8];
    const float* lg = (const float*)d_in[9];
    const float* lb = (const float*)d_in[10];
    float* out = (float*)d_out;

    char* ws = (char*)d_ws;
    u16* xb = (u16*)(ws + 0);
    u16* wt = (u16*)(ws + 16777216);
    u16* q  = (u16*)(ws + 25165824);
    u16* k  = (u16*)(ws + 41943040);
    u16* vt = (u16*)(ws + 75497472);
    u16* cx = (u16*)(ws + 92274688);
    u16* y16 = (u16*)(ws + 109051904);

    convert_kernel<<<5120, 256, 0, stream>>>(x, xb, Wq, Wk, Wv, Wo, wt);

    gemm256_kernel<0><<<768, 512, 0, stream>>>(xb, wt, bq, bk, bv, q, k, vt);
    attn_kernel<<<dim3(64, 8), 512, 0, stream>>>(q, k, vt, cx);
    gemm256_kernel<1><<<256, 512, 0, stream>>>(cx, wt + 3145728, bo, nullptr,
                                               nullptr, y16, xb, nullptr);
    ln_kernel<<<8192, 256, 0, stream>>>(y16, lg, lb, out);
}

// Round 15
// 172.747 us; speedup vs baseline: 1.1380x; 1.0236x over previous
//
#include <hip/hip_runtime.h>

// Problem constants: B=4, T=2048, D=1024, H=16, DK=64, M = B*T = 8192.
// Workspace layout (bytes):
//   xb  @ 0         : x as fp16            (16 MB)   (also residual source)
//   wt  @ 16 MB     : Wq,Wk,Wv,Wo transposed [N][K] fp16 (4 x 2 MB)
//   q   @ 24 MB     : Q (pre-scaled by log2e/8) [B*T, D] fp16 (16 MB)
//   k   @ 40 MB     : K  [B*T, D] fp16     (16 MB)
//   vt  @ 72 MB     : V^T [B*H][64][T] fp16(16 MB)  <- written by QKV epilogue
//   cx  @ 88 MB     : attention ctx fp16   (16 MB)
//   y   @ 104 MB    : pre-LN fp16          (16 MB)

using u16 = unsigned short;
using u32 = unsigned int;
typedef _Float16 f16x8 __attribute__((ext_vector_type(8)));
typedef __fp16 h16x2 __attribute__((ext_vector_type(2)));   // cvt_pkrtz/fdot2 type
typedef float f32x4 __attribute__((ext_vector_type(4)));
typedef unsigned short u16x8 __attribute__((ext_vector_type(8)));
typedef unsigned short u16x4 __attribute__((ext_vector_type(4)));

template <bool B> struct BoolTag { static constexpr bool v = B; };

__device__ inline u16 f2h_bits(float f) {
    _Float16 h = (_Float16)f;
    return __builtin_bit_cast(u16, h);
}
__device__ inline float h2f(u16 u) {
    return (float)__builtin_bit_cast(_Float16, u);
}

__device__ __forceinline__ void gload16(const void* g, void* l) {
    __builtin_amdgcn_global_load_lds(
        (const __attribute__((address_space(1))) void*)g,
        (__attribute__((address_space(3))) void*)l, 16, 0, 0);
}

// -------------------------- fused converts: x -> fp16, W^T x4 -> fp16
// blocks 0..4095: x;  blocks 4096..5119: weight tiles (z = wb>>8).
__global__ __launch_bounds__(256) void convert_kernel(
    const float* __restrict__ x, u16* __restrict__ xb,
    const float* __restrict__ W0, const float* __restrict__ W1,
    const float* __restrict__ W2, const float* __restrict__ W3,
    u16* __restrict__ Wt) {
    __shared__ float ts[64][68];
    const int bid = blockIdx.x, tid = threadIdx.x;
    if (bid < 4096) {
        size_t i = ((size_t)bid * 256 + tid) * 8;
        float4 a = *(const float4*)(x + i);
        float4 b = *(const float4*)(x + i + 4);
        u16x8 o;
        o[0] = f2h_bits(a.x); o[1] = f2h_bits(a.y); o[2] = f2h_bits(a.z); o[3] = f2h_bits(a.w);
        o[4] = f2h_bits(b.x); o[5] = f2h_bits(b.y); o[6] = f2h_bits(b.z); o[7] = f2h_bits(b.w);
        *(u16x8*)(xb + i) = o;
        return;
    }
    const int wb = bid - 4096;
    const int z = wb >> 8, rem = wb & 255;
    const float* W = z == 0 ? W0 : (z == 1 ? W1 : (z == 2 ? W2 : W3));
    u16* Wo = Wt + (size_t)z * 1048576;
    const int k0 = (rem >> 4) * 64, n0 = (rem & 15) * 64;
    const int rr = tid >> 3, c = tid & 7;
#pragma unroll
    for (int p = 0; p < 2; p++) {
        int k = p * 32 + rr;
        float4 u = *(const float4*)(W + (size_t)(k0 + k) * 1024 + n0 + c * 8);
        float4 w = *(const float4*)(W + (size_t)(k0 + k) * 1024 + n0 + c * 8 + 4);
        *(float4*)&ts[k][c * 8] = u;
        *(float4*)&ts[k][c * 8 + 4] = w;
    }
    __syncthreads();
#pragma unroll
    for (int p = 0; p < 2; p++) {
        int n = p * 32 + rr;
        u16 o[8];
#pragma unroll
        for (int j = 0; j < 8; j++) o[j] = f2h_bits(ts[c * 8 + j][n]);
        *(u16x8*)(Wo + (size_t)(n0 + n) * 1024 + k0 + c * 8) = *(u16x8*)o;
    }
}

// --------------------------------------------------------- 128x256 GEMM
// C[M,N] = A[M,1024] @ W (W as Wt[N][1024] fp16). BM=128, BN=256, BK=64.
// 512 threads = 8 waves (2M x 4N), per-wave 64x64. Triple-buffered LDS,
// m201-style phases, counted vmcnt(6) per K-tile.
// MODE 0: QKV fused (N=3072): Q/K fp16 out + bias (+log2e/8 scale on Q);
//         V blocks transpose in-LDS (stride 134) and write vt directly.
// MODE 1: Wo: y16 = fp16(acc + bias + residual_fp16); qo=y16 out, ko=xb.
template <int MODE>
__global__ __launch_bounds__(512) void gemm256_kernel(
    const u16* __restrict__ A, const u16* __restrict__ Wt,
    const float* __restrict__ b0, const float* __restrict__ b1,
    const float* __restrict__ b2, u16* __restrict__ qo, u16* __restrict__ ko,
    u16* __restrict__ vt) {
    constexpr int NBY = (MODE == 0) ? 12 : 4;
    __shared__ u16 As[3][128 * 64];
    __shared__ u16 Bs[3][256 * 64];

    const int bid = blockIdx.x;
    const int cpx = (MODE == 0) ? 96 : 32;        // gridDim/8, grid%8==0
    const int swz = (bid & 7) * cpx + (bid >> 3); // XCD-contiguous
    const int bx = swz / NBY, by = swz % NBY;
    const size_t row0 = (size_t)bx * 128;
    const size_t col0 = (size_t)by * 256;

    const int tid = threadIdx.x, lane = tid & 63;
    const int wid = tid >> 6, wm = wid >> 2, wn = wid & 3;
    const int l15 = lane & 15, lg = lane >> 4;
    const int rr = tid >> 3, c8 = tid & 7;
    const int scw = (c8 ^ (rr & 7)) * 8;          // pre-swizzled source chunk

    f32x4 acc[4][4] = {};

    auto stage_half = [&](int kt, u16* dA, u16* dB, int h) {
        const int k0 = kt * 64;
        if (h == 0) {
            gload16(A + (row0 + rr) * 1024 + k0 + scw, dA + tid * 8);
            gload16(Wt + (col0 + rr) * 1024 + k0 + scw, dB + tid * 8);
            gload16(Wt + (col0 + 64 + rr) * 1024 + k0 + scw, dB + (512 + tid) * 8);
        } else {
            gload16(A + (row0 + 64 + rr) * 1024 + k0 + scw, dA + (512 + tid) * 8);
            gload16(Wt + (col0 + 128 + rr) * 1024 + k0 + scw, dB + (1024 + tid) * 8);
            gload16(Wt + (col0 + 192 + rr) * 1024 + k0 + scw, dB + (1536 + tid) * 8);
        }
    };

    auto ldops = [&](const u16* bA, const u16* bB, int kcv, f16x8* Af, f16x8* Bf) {
        const int swo = ((kcv * 4 + lg) ^ (l15 & 7)) * 8;
#pragma unroll
        for (int n = 0; n < 4; n++)
            Bf[n] = *(const f16x8*)(bB + (wn * 64 + n * 16 + l15) * 64 + swo);
#pragma unroll
        for (int m = 0; m < 4; m++)
            Af[m] = *(const f16x8*)(bA + (wm * 64 + m * 16 + l15) * 64 + swo);
    };

    auto domfma = [&](const f16x8* Af, const f16x8* Bf) {
        __builtin_amdgcn_s_setprio(1);
#pragma unroll
        for (int m = 0; m < 4; m++)
#pragma unroll
            for (int n = 0; n < 4; n++)
                acc[m][n] = __builtin_amdgcn_mfma_f32_16x16x32_f16(
                    Af[m], Bf[n], acc[m][n], 0, 0, 0);
        __builtin_amdgcn_s_setprio(0);
    };

    u16 *pA = &As[0][0], *pnA = &As[1][0], *ppA = &As[2][0];
    u16 *pB = &Bs[0][0], *pnB = &Bs[1][0], *ppB = &Bs[2][0];

    stage_half(0, pA, pB, 0);
    stage_half(0, pA, pB, 1);
    stage_half(1, pnA, pnB, 0);
    stage_half(1, pnA, pnB, 1);
    asm volatile("s_waitcnt vmcnt(6)" ::: "memory");
    __builtin_amdgcn_sched_barrier(0);
    __builtin_amdgcn_s_barrier();

#pragma unroll 1
    for (int t = 0; t < 16; t++) {
        f16x8 af[4], bf[4];
        ldops(pA, pB, 0, af, bf);
        if (t < 14) stage_half(t + 2, ppA, ppB, 0);
        __builtin_amdgcn_sched_barrier(0);
        __builtin_amdgcn_s_barrier();
        asm volatile("s_waitcnt lgkmcnt(0)" ::: "memory");
        __builtin_amdgcn_sched_barrier(0);
        domfma(af, bf);
        __builtin_amdgcn_sched_barrier(0);
        __builtin_amdgcn_s_barrier();
        ldops(pA, pB, 1, af, bf);
        if (t < 14) stage_half(t + 2, ppA, ppB, 1);
        if (t < 14)       asm volatile("s_waitcnt vmcnt(6)" ::: "memory");
        else if (t == 14) asm volatile("s_waitcnt vmcnt(0)" ::: "memory");
        __builtin_amdgcn_sched_barrier(0);
        __builtin_amdgcn_s_barrier();
        asm volatile("s_waitcnt lgkmcnt(0)" ::: "memory");
        __builtin_amdgcn_sched_barrier(0);
        domfma(af, bf);
        __builtin_amdgcn_sched_barrier(0);
        if (t < 15) {
            __builtin_amdgcn_s_barrier();
            u16* tp;
            tp = pA; pA = pnA; pnA = ppA; ppA = tp;
            tp = pB; pB = pnB; pnB = ppB; ppB = tp;
        }
    }

    if (MODE == 0) {
        const int zsel = by >> 2;  // 0=Q, 1=K, 2=V
        if (zsel < 2) {
            u16* ob = zsel == 0 ? qo : ko;
            const float* bias = zsel == 0 ? b0 : b1;
            const float qs = zsel == 0 ? 0.18033688f : 1.0f;  // log2(e)/8 on Q
#pragma unroll
            for (int m = 0; m < 4; m++) {
#pragma unroll
                for (int n = 0; n < 4; n++) {
                    size_t col = col0 + wn * 64 + n * 16 + l15;
                    size_t colz = col & 1023;
                    float bb = bias[colz];
#pragma unroll
                    for (int r = 0; r < 4; r++) {
                        size_t row = row0 + wm * 64 + m * 16 + lg * 4 + r;
                        ob[row * 1024 + colz] = f2h_bits((acc[m][n][r] + bb) * qs);
                    }
                }
            }
        } else {
            // V: bias + in-LDS transpose -> vt[(b*16+h)*64+d][t]
            u16* TL = &Bs[0][0];  // [256][134] u16 = 68608 B (Bs is 98304 B)
            __syncthreads();
#pragma unroll
            for (int m = 0; m < 4; m++) {
#pragma unroll
                for (int n = 0; n < 4; n++) {
                    int cl = wn * 64 + n * 16 + l15;
                    float bb = b2[(col0 & 1023) + cl];
#pragma unroll
                    for (int r = 0; r < 4; r++) {
                        int rl = wm * 64 + m * 16 + lg * 4 + r;
                        TL[cl * 134 + rl] = f2h_bits(acc[m][n][r] + bb);
                    }
                }
            }
            __syncthreads();
            const int vrl = tid >> 1, th = tid & 1;
            size_t vrow = (row0 >> 11) * 1024 + (col0 & 1023) + vrl;
            const int t0loc = (int)(row0 & 2047) + th * 64;
#pragma unroll
            for (int j = 0; j < 8; j++)
                *(u16x8*)(vt + vrow * 2048 + t0loc + j * 8) =
                    *(const u16x8*)(TL + vrl * 134 + th * 64 + j * 8);
        }
    } else {
        // Wo: y16 = fp16(acc + bias + fp16 residual from xb)
        u16* yo = qo;
        const u16* xres = ko;
#pragma unroll
        for (int m = 0; m < 4; m++) {
#pragma unroll
            for (int n = 0; n < 4; n++) {
                size_t col = col0 + wn * 64 + n * 16 + l15;
                float bb = b0[col];
#pragma unroll
                for (int r = 0; r < 4; r++) {
                    size_t row = row0 + wm * 64 + m * 16 + lg * 4 + r;
                    size_t idx = row * 1024 + col;
                    yo[idx] = f2h_bits(acc[m][n][r] + bb + h2f(xres[idx]));
                }
            }
        }
    }
}

// ------------------------------------------------------------- attention v9
// 8 waves x 32 q = 256 q/block, KV steps of 64, grid (64 bh, 8 qb big-first)
// = 512 blocks, 2 blocks/CU. COUNTED-VMCNT pipeline (no __syncthreads vmcnt(0)
// drain): body -> raw barrier -> stage(s+128 over cur) -> vmcnt(2) (waits the
// s+64 loads issued a FULL STEP ago) -> raw barrier -> swap. exp2-direct
// softmax, fdot2 psum, swapped QK^T, packed P via padded [16][72] P-LDS.
__global__ __launch_bounds__(512) void attn_kernel(const u16* __restrict__ Q,
                                                   const u16* __restrict__ Kb,
                                                   const u16* __restrict__ Vt,
                                                   u16* __restrict__ ctx) {
    __shared__ u16 Ks[2][64 * 64];
    __shared__ u16 Vs[2][64 * 64];
    __shared__ u16 Ps[8][2][16][72];

    const int bh = blockIdx.x;
    const int b = bh >> 4, h = bh & 15;
    const int qb = 7 - (int)blockIdx.y;  // big blocks dispatch first
    const int tid = threadIdx.x, lane = tid & 63, wid = tid >> 6;
    const int l15 = lane & 15, lg = lane >> 4;
    const int q0w = qb * 256 + wid * 32;
    const int send = qb * 256;

    const int rr = tid >> 3, c8 = tid & 7;
    const int scw = (c8 ^ (rr & 7)) * 8;
    const size_t kbase = ((size_t)b * 2048) * 1024 + h * 64 + scw;
    const size_t vbase = ((size_t)bh * 64 + rr) * 2048 + scw;

    f16x8 qv[2][2];
#pragma unroll
    for (int qf = 0; qf < 2; qf++) {
        size_t qoff = ((size_t)b * 2048 + q0w + qf * 16 + l15) * 1024 + h * 64 + lg * 8;
        qv[qf][0] = *(const f16x8*)(Q + qoff);
        qv[qf][1] = *(const f16x8*)(Q + qoff + 32);
    }

    const int swk0 = (lg ^ (l15 & 7)) * 8;
    const int swk1 = ((4 + lg) ^ (l15 & 7)) * 8;
    u16* Pw0 = &Ps[wid][0][0][0] + l15 * 72;
    u16* Pw1 = &Ps[wid][1][0][0] + l15 * 72;

    const h16x2 one2 = {(__fp16)1.0f, (__fp16)1.0f};

    f32x4 acc[2][4] = {};
    float psum[2] = {0.0f, 0.0f};

    auto stage = [&](int s, int bf) {
        gload16(Kb + kbase + (size_t)(s + rr) * 1024, Ks[bf] + tid * 8);
        gload16(Vt + vbase + s, Vs[bf] + tid * 8);
    };

    auto body = [&](int s, int bf, auto maskc) {
        constexpr bool MASK = decltype(maskc)::v;
#pragma unroll
        for (int c = 0; c < 4; c++) {
            const u16* kp = Ks[bf] + (c * 16 + l15) * 64;
            f16x8 kf0 = *(const f16x8*)(kp + swk0);
            f16x8 kf1 = *(const f16x8*)(kp + swk1);
#pragma unroll
            for (int qf = 0; qf < 2; qf++) {
                f32x4 z = {};
                z = __builtin_amdgcn_mfma_f32_16x16x32_f16(kf0, qv[qf][0], z, 0, 0, 0);
                z = __builtin_amdgcn_mfma_f32_16x16x32_f16(kf1, qv[qf][1], z, 0, 0, 0);
                float p0 = __builtin_amdgcn_exp2f(z[0]);
                float p1 = __builtin_amdgcn_exp2f(z[1]);
                float p2 = __builtin_amdgcn_exp2f(z[2]);
                float p3 = __builtin_amdgcn_exp2f(z[3]);
                if (MASK) {
                    int kk = s + c * 16 + lg * 4;
                    int qq = q0w + qf * 16 + l15;
                    p0 = (kk + 0 <= qq) ? p0 : 0.0f;
                    p1 = (kk + 1 <= qq) ? p1 : 0.0f;
                    p2 = (kk + 2 <= qq) ? p2 : 0.0f;
                    p3 = (kk + 3 <= qq) ? p3 : 0.0f;
                }
                h16x2 w0 = __builtin_amdgcn_cvt_pkrtz(p0, p1);
                h16x2 w1 = __builtin_amdgcn_cvt_pkrtz(p2, p3);
                psum[qf] = __builtin_amdgcn_fdot2(w0, one2, psum[qf], false);
                psum[qf] = __builtin_amdgcn_fdot2(w1, one2, psum[qf], false);
                uint2 w;
                w.x = __builtin_bit_cast(u32, w0);
                w.y = __builtin_bit_cast(u32, w1);
                *(uint2*)((qf ? Pw1 : Pw0) + c * 16 + lg * 4) = w;
            }
        }
        f16x8 pa0[2], pa1[2];
#pragma unroll
        for (int qf = 0; qf < 2; qf++) {
            const u16* Pw = qf ? Pw1 : Pw0;
            pa0[qf] = *(const f16x8*)(Pw + lg * 8);
            pa1[qf] = *(const f16x8*)(Pw + 32 + lg * 8);
        }
#pragma unroll
        for (int dt = 0; dt < 4; dt++) {
            const u16* vp = Vs[bf] + (dt * 16 + l15) * 64;
            f16x8 vf0 = *(const f16x8*)(vp + swk0);
            f16x8 vf1 = *(const f16x8*)(vp + swk1);
#pragma unroll
            for (int qf = 0; qf < 2; qf++) {
                acc[qf][dt] =
                    __builtin_amdgcn_mfma_f32_16x16x32_f16(pa0[qf], vf0, acc[qf][dt], 0, 0, 0);
                acc[qf][dt] =
                    __builtin_amdgcn_mfma_f32_16x16x32_f16(pa1[qf], vf1, acc[qf][dt], 0, 0, 0);
            }
        }
    };

    // prologue: tiles 0 and 64 in flight; wait tile 0 only (vmcnt(2))
    stage(0, 0);
    stage(64, 1);
    asm volatile("s_waitcnt vmcnt(2)" ::: "memory");
    __builtin_amdgcn_sched_barrier(0);
    __builtin_amdgcn_s_barrier();

    int cur = 0;
#pragma unroll 1
    for (int s = 0; s < send; s += 64) {
        body(s, cur, BoolTag<false>{});
        __builtin_amdgcn_sched_barrier(0);
        __builtin_amdgcn_s_barrier();              // all waves done reading cur
        stage(s + 128, cur);                        // overwrite cur with s+128
        asm volatile("s_waitcnt vmcnt(2)" ::: "memory");  // s+64 landed (aged 1 step)
        __builtin_amdgcn_sched_barrier(0);
        __builtin_amdgcn_s_barrier();
        cur ^= 1;
    }
    // diagonal tail: 4 masked steps; wave wid participates iff wid >= 2j.
#pragma unroll 1
    for (int j = 0; j < 4; j++) {
        if (wid >= 2 * j) body(send + 64 * j, cur, BoolTag<true>{});
        __builtin_amdgcn_sched_barrier(0);
        __builtin_amdgcn_s_barrier();
        if (j < 2) {
            stage(send + 64 * (j + 2), cur);
            asm volatile("s_waitcnt vmcnt(2)" ::: "memory");
        } else if (j == 2) {
            asm volatile("s_waitcnt vmcnt(0)" ::: "memory");
        }
        __builtin_amdgcn_sched_barrier(0);
        __builtin_amdgcn_s_barrier();
        cur ^= 1;
    }

#pragma unroll
    for (int qf = 0; qf < 2; qf++) {
        psum[qf] += __shfl_xor(psum[qf], 16);
        psum[qf] += __shfl_xor(psum[qf], 32);
    }
#pragma unroll
    for (int qf = 0; qf < 2; qf++) {
        float inv = 1.0f / psum[qf];
#pragma unroll
        for (int r = 0; r < 4; r++) {
            float ir = __shfl(inv, lg * 4 + r);
            size_t row = (size_t)b * 2048 + q0w + qf * 16 + lg * 4 + r;
#pragma unroll
            for (int dt = 0; dt < 4; dt++)
                ctx[row * 1024 + h * 64 + dt * 16 + l15] = f2h_bits(acc[qf][dt][r] * ir);
        }
    }
}

// -------------------------------------------------------------- layer norm
// y in fp16 (16 MB read vs 32), out f32.
__global__ __launch_bounds__(256) void ln_kernel(const u16* __restrict__ y,
                                                 const float* __restrict__ g,
                                                 const float* __restrict__ bb,
                                                 float* __restrict__ out) {
    const int r = blockIdx.x, tid = threadIdx.x;
    u16x4 v4 = *(const u16x4*)(y + (size_t)r * 1024 + tid * 4);
    float vx = h2f(v4[0]), vy = h2f(v4[1]), vz = h2f(v4[2]), vw = h2f(v4[3]);
    float s = vx + vy + vz + vw;
    float sq = vx * vx + vy * vy + vz * vz + vw * vw;
#pragma unroll
    for (int ofs = 1; ofs < 64; ofs <<= 1) {
        s += __shfl_xor(s, ofs);
        sq += __shfl_xor(sq, ofs);
    }
    __shared__ float as[4], aq[4];
    if ((tid & 63) == 0) { as[tid >> 6] = s; aq[tid >> 6] = sq; }
    __syncthreads();
    s = as[0] + as[1] + as[2] + as[3];
    sq = aq[0] + aq[1] + aq[2] + aq[3];
    float mu = s * (1.0f / 1024.0f);
    float var = sq * (1.0f / 1024.0f) - mu * mu;
    float rstd = rsqrtf(var + 1e-5f);
    float4 gv = *(const float4*)(g + tid * 4);
    float4 bv = *(const float4*)(bb + tid * 4);
    float4 o4;
    o4.x = (vx - mu) * rstd * gv.x + bv.x;
    o4.y = (vy - mu) * rstd * gv.y + bv.y;
    o4.z = (vz - mu) * rstd * gv.z + bv.z;
    o4.w = (vw - mu) * rstd * gv.w + bv.w;
    *(float4*)(out + (size_t)r * 1024 + tid * 4) = o4;
}

// ------------------------------------------------------------------ launch
extern "C" void kernel_launch(void* const* d_in, const int* in_sizes, int n_in,
                              void* d_out, int out_size, void* d_ws, size_t ws_size,
                              hipStream_t stream) {
    const float* x  = (const float*)d_in[0];
    const float* Wq = (const float*)d_in[1];
    const float* bq = (const float*)d_in[2];
    const float* Wk = (const float*)d_in[3];
    const float* bk = (const float*)d_in[4];
    const float* Wv = (const float*)d_in[5];
    const float* bv = (const float*)d_in[6];
    const float* Wo = (const float*)d_in[7];
    const float* bo = (const float*)d_in[8];
    const float* lg = (const float*)d_in[9];
    const float* lb = (const float*)d_in[10];
    float* out = (float*)d_out;

    char* ws = (char*)d_ws;
    u16* xb = (u16*)(ws + 0);
    u16* wt = (u16*)(ws + 16777216);
    u16* q  = (u16*)(ws + 25165824);
    u16* k  = (u16*)(ws + 41943040);
    u16* vt = (u16*)(ws + 75497472);
    u16* cx = (u16*)(ws + 92274688);
    u16* y16 = (u16*)(ws + 109051904);

    convert_kernel<<<5120, 256, 0, stream>>>(x, xb, Wq, Wk, Wv, Wo, wt);

    gemm256_kernel<0><<<768, 512, 0, stream>>>(xb, wt, bq, bk, bv, q, k, vt);
    attn_kernel<<<dim3(64, 8), 512, 0, stream>>>(q, k, vt, cx);
    gemm256_kernel<1><<<256, 512, 0, stream>>>(cx, wt + 3145728, bo, nullptr,
                                               nullptr, y16, xb, nullptr);
    ln_kernel<<<8192, 256, 0, stream>>>(y16, lg, lb, out);
}

// Round 16
// 171.044 us; speedup vs baseline: 1.1493x; 1.0100x over previous
//
#include <hip/hip_runtime.h>

// Problem constants: B=4, T=2048, D=1024, H=16, DK=64, M = B*T = 8192.
// Workspace layout (bytes):
//   xb  @ 0         : x as fp16            (16 MB)   (also residual source)
//   wt  @ 16 MB     : Wq,Wk,Wv,Wo transposed [N][K] fp16 (4 x 2 MB)
//   q   @ 24 MB     : Q (pre-scaled by log2e/8) [B*T, D] fp16 (16 MB)
//   k   @ 40 MB     : K  [B*T, D] fp16     (16 MB)
//   vt  @ 72 MB     : V^T [B*H][64][T] fp16(16 MB)  <- written by QKV epilogue
//   cx  @ 88 MB     : attention ctx fp16   (16 MB)
//   y   @ 104 MB    : pre-LN fp16          (16 MB)

using u16 = unsigned short;
using u32 = unsigned int;
typedef _Float16 f16x8 __attribute__((ext_vector_type(8)));
typedef __fp16 h16x2 __attribute__((ext_vector_type(2)));   // cvt_pkrtz/fdot2 type
typedef float f32x4 __attribute__((ext_vector_type(4)));
typedef unsigned short u16x8 __attribute__((ext_vector_type(8)));
typedef unsigned short u16x4 __attribute__((ext_vector_type(4)));
typedef unsigned int u32x4 __attribute__((ext_vector_type(4)));

#if __has_builtin(__builtin_amdgcn_permlane16_swap) && \
    __has_builtin(__builtin_amdgcn_permlane32_swap)
#define HAVE_PERMLANE 1
#else
#define HAVE_PERMLANE 0
#endif

template <bool B> struct BoolTag { static constexpr bool v = B; };

__device__ inline u16 f2h_bits(float f) {
    _Float16 h = (_Float16)f;
    return __builtin_bit_cast(u16, h);
}
__device__ inline float h2f(u16 u) {
    return (float)__builtin_bit_cast(_Float16, u);
}

__device__ __forceinline__ void gload16(const void* g, void* l) {
    __builtin_amdgcn_global_load_lds(
        (const __attribute__((address_space(1))) void*)g,
        (__attribute__((address_space(3))) void*)l, 16, 0, 0);
}

// -------------------------- fused converts: x -> fp16, W^T x4 -> fp16
// blocks 0..4095: x;  blocks 4096..5119: weight tiles (z = wb>>8).
__global__ __launch_bounds__(256) void convert_kernel(
    const float* __restrict__ x, u16* __restrict__ xb,
    const float* __restrict__ W0, const float* __restrict__ W1,
    const float* __restrict__ W2, const float* __restrict__ W3,
    u16* __restrict__ Wt) {
    __shared__ float ts[64][68];
    const int bid = blockIdx.x, tid = threadIdx.x;
    if (bid < 4096) {
        size_t i = ((size_t)bid * 256 + tid) * 8;
        float4 a = *(const float4*)(x + i);
        float4 b = *(const float4*)(x + i + 4);
        u16x8 o;
        o[0] = f2h_bits(a.x); o[1] = f2h_bits(a.y); o[2] = f2h_bits(a.z); o[3] = f2h_bits(a.w);
        o[4] = f2h_bits(b.x); o[5] = f2h_bits(b.y); o[6] = f2h_bits(b.z); o[7] = f2h_bits(b.w);
        *(u16x8*)(xb + i) = o;
        return;
    }
    const int wb = bid - 4096;
    const int z = wb >> 8, rem = wb & 255;
    const float* W = z == 0 ? W0 : (z == 1 ? W1 : (z == 2 ? W2 : W3));
    u16* Wo = Wt + (size_t)z * 1048576;
    const int k0 = (rem >> 4) * 64, n0 = (rem & 15) * 64;
    const int rr = tid >> 3, c = tid & 7;
#pragma unroll
    for (int p = 0; p < 2; p++) {
        int k = p * 32 + rr;
        float4 u = *(const float4*)(W + (size_t)(k0 + k) * 1024 + n0 + c * 8);
        float4 w = *(const float4*)(W + (size_t)(k0 + k) * 1024 + n0 + c * 8 + 4);
        *(float4*)&ts[k][c * 8] = u;
        *(float4*)&ts[k][c * 8 + 4] = w;
    }
    __syncthreads();
#pragma unroll
    for (int p = 0; p < 2; p++) {
        int n = p * 32 + rr;
        u16 o[8];
#pragma unroll
        for (int j = 0; j < 8; j++) o[j] = f2h_bits(ts[c * 8 + j][n]);
        *(u16x8*)(Wo + (size_t)(n0 + n) * 1024 + k0 + c * 8) = *(u16x8*)o;
    }
}

// --------------------------------------------------------- 128x256 GEMM
// C[M,N] = A[M,1024] @ W (W as Wt[N][1024] fp16). BM=128, BN=256, BK=64.
// 512 threads = 8 waves (2M x 4N), per-wave 64x64. Triple-buffered LDS,
// m201-style phases, counted vmcnt(6) per K-tile.
// MODE 0: QKV fused (N=3072): Q/K fp16 out + bias (+log2e/8 scale on Q);
//         V blocks transpose in-LDS (stride 134) and write vt directly.
// MODE 1: Wo: y16 = fp16(acc + bias + residual_fp16); qo=y16 out, ko=xb.
template <int MODE>
__global__ __launch_bounds__(512) void gemm256_kernel(
    const u16* __restrict__ A, const u16* __restrict__ Wt,
    const float* __restrict__ b0, const float* __restrict__ b1,
    const float* __restrict__ b2, u16* __restrict__ qo, u16* __restrict__ ko,
    u16* __restrict__ vt) {
    constexpr int NBY = (MODE == 0) ? 12 : 4;
    __shared__ u16 As[3][128 * 64];
    __shared__ u16 Bs[3][256 * 64];

    const int bid = blockIdx.x;
    const int cpx = (MODE == 0) ? 96 : 32;        // gridDim/8, grid%8==0
    const int swz = (bid & 7) * cpx + (bid >> 3); // XCD-contiguous
    const int bx = swz / NBY, by = swz % NBY;
    const size_t row0 = (size_t)bx * 128;
    const size_t col0 = (size_t)by * 256;

    const int tid = threadIdx.x, lane = tid & 63;
    const int wid = tid >> 6, wm = wid >> 2, wn = wid & 3;
    const int l15 = lane & 15, lg = lane >> 4;
    const int rr = tid >> 3, c8 = tid & 7;
    const int scw = (c8 ^ (rr & 7)) * 8;          // pre-swizzled source chunk

    f32x4 acc[4][4] = {};

    auto stage_half = [&](int kt, u16* dA, u16* dB, int h) {
        const int k0 = kt * 64;
        if (h == 0) {
            gload16(A + (row0 + rr) * 1024 + k0 + scw, dA + tid * 8);
            gload16(Wt + (col0 + rr) * 1024 + k0 + scw, dB + tid * 8);
            gload16(Wt + (col0 + 64 + rr) * 1024 + k0 + scw, dB + (512 + tid) * 8);
        } else {
            gload16(A + (row0 + 64 + rr) * 1024 + k0 + scw, dA + (512 + tid) * 8);
            gload16(Wt + (col0 + 128 + rr) * 1024 + k0 + scw, dB + (1024 + tid) * 8);
            gload16(Wt + (col0 + 192 + rr) * 1024 + k0 + scw, dB + (1536 + tid) * 8);
        }
    };

    auto ldops = [&](const u16* bA, const u16* bB, int kcv, f16x8* Af, f16x8* Bf) {
        const int swo = ((kcv * 4 + lg) ^ (l15 & 7)) * 8;
#pragma unroll
        for (int n = 0; n < 4; n++)
            Bf[n] = *(const f16x8*)(bB + (wn * 64 + n * 16 + l15) * 64 + swo);
#pragma unroll
        for (int m = 0; m < 4; m++)
            Af[m] = *(const f16x8*)(bA + (wm * 64 + m * 16 + l15) * 64 + swo);
    };

    auto domfma = [&](const f16x8* Af, const f16x8* Bf) {
        __builtin_amdgcn_s_setprio(1);
#pragma unroll
        for (int m = 0; m < 4; m++)
#pragma unroll
            for (int n = 0; n < 4; n++)
                acc[m][n] = __builtin_amdgcn_mfma_f32_16x16x32_f16(
                    Af[m], Bf[n], acc[m][n], 0, 0, 0);
        __builtin_amdgcn_s_setprio(0);
    };

    u16 *pA = &As[0][0], *pnA = &As[1][0], *ppA = &As[2][0];
    u16 *pB = &Bs[0][0], *pnB = &Bs[1][0], *ppB = &Bs[2][0];

    stage_half(0, pA, pB, 0);
    stage_half(0, pA, pB, 1);
    stage_half(1, pnA, pnB, 0);
    stage_half(1, pnA, pnB, 1);
    asm volatile("s_waitcnt vmcnt(6)" ::: "memory");
    __builtin_amdgcn_sched_barrier(0);
    __builtin_amdgcn_s_barrier();

#pragma unroll 1
    for (int t = 0; t < 16; t++) {
        f16x8 af[4], bf[4];
        ldops(pA, pB, 0, af, bf);
        if (t < 14) stage_half(t + 2, ppA, ppB, 0);
        __builtin_amdgcn_sched_barrier(0);
        __builtin_amdgcn_s_barrier();
        asm volatile("s_waitcnt lgkmcnt(0)" ::: "memory");
        __builtin_amdgcn_sched_barrier(0);
        domfma(af, bf);
        __builtin_amdgcn_sched_barrier(0);
        __builtin_amdgcn_s_barrier();
        ldops(pA, pB, 1, af, bf);
        if (t < 14) stage_half(t + 2, ppA, ppB, 1);
        if (t < 14)       asm volatile("s_waitcnt vmcnt(6)" ::: "memory");
        else if (t == 14) asm volatile("s_waitcnt vmcnt(0)" ::: "memory");
        __builtin_amdgcn_sched_barrier(0);
        __builtin_amdgcn_s_barrier();
        asm volatile("s_waitcnt lgkmcnt(0)" ::: "memory");
        __builtin_amdgcn_sched_barrier(0);
        domfma(af, bf);
        __builtin_amdgcn_sched_barrier(0);
        if (t < 15) {
            __builtin_amdgcn_s_barrier();
            u16* tp;
            tp = pA; pA = pnA; pnA = ppA; ppA = tp;
            tp = pB; pB = pnB; pnB = ppB; ppB = tp;
        }
    }

    if (MODE == 0) {
        const int zsel = by >> 2;  // 0=Q, 1=K, 2=V
        if (zsel < 2) {
            u16* ob = zsel == 0 ? qo : ko;
            const float* bias = zsel == 0 ? b0 : b1;
            const float qs = zsel == 0 ? 0.18033688f : 1.0f;  // log2(e)/8 on Q
#pragma unroll
            for (int m = 0; m < 4; m++) {
#pragma unroll
                for (int n = 0; n < 4; n++) {
                    size_t col = col0 + wn * 64 + n * 16 + l15;
                    size_t colz = col & 1023;
                    float bb = bias[colz];
#pragma unroll
                    for (int r = 0; r < 4; r++) {
                        size_t row = row0 + wm * 64 + m * 16 + lg * 4 + r;
                        ob[row * 1024 + colz] = f2h_bits((acc[m][n][r] + bb) * qs);
                    }
                }
            }
        } else {
            // V: bias + in-LDS transpose -> vt[(b*16+h)*64+d][t]
            u16* TL = &Bs[0][0];  // [256][134] u16 = 68608 B (Bs is 98304 B)
            __syncthreads();
#pragma unroll
            for (int m = 0; m < 4; m++) {
#pragma unroll
                for (int n = 0; n < 4; n++) {
                    int cl = wn * 64 + n * 16 + l15;
                    float bb = b2[(col0 & 1023) + cl];
#pragma unroll
                    for (int r = 0; r < 4; r++) {
                        int rl = wm * 64 + m * 16 + lg * 4 + r;
                        TL[cl * 134 + rl] = f2h_bits(acc[m][n][r] + bb);
                    }
                }
            }
            __syncthreads();
            const int vrl = tid >> 1, th = tid & 1;
            size_t vrow = (row0 >> 11) * 1024 + (col0 & 1023) + vrl;
            const int t0loc = (int)(row0 & 2047) + th * 64;
#pragma unroll
            for (int j = 0; j < 8; j++)
                *(u16x8*)(vt + vrow * 2048 + t0loc + j * 8) =
                    *(const u16x8*)(TL + vrl * 134 + th * 64 + j * 8);
        }
    } else {
        // Wo: y16 = fp16(acc + bias + fp16 residual from xb)
        u16* yo = qo;
        const u16* xres = ko;
#pragma unroll
        for (int m = 0; m < 4; m++) {
#pragma unroll
            for (int n = 0; n < 4; n++) {
                size_t col = col0 + wn * 64 + n * 16 + l15;
                float bb = b0[col];
#pragma unroll
                for (int r = 0; r < 4; r++) {
                    size_t row = row0 + wm * 64 + m * 16 + lg * 4 + r;
                    size_t idx = row * 1024 + col;
                    yo[idx] = f2h_bits(acc[m][n][r] + bb + h2f(xres[idx]));
                }
            }
        }
    }
}

// ------------------------------------------------------------ attention v10
// 8 waves x 32 q = 256 q/block, KV steps of 64, grid (64 bh, 8 qb big-first)
// = 512 blocks, 2 blocks/CU. Counted-vmcnt K/V pipeline (round-15). NEW: T12
// in-register P redistribution — permlane32_swap + permlane16_swap convert the
// QK^T C-layout (lane holds P[k=c*16+lg*4+r][q=l15]) directly into the PV
// A-fragment (lane needs P[q=l15][k=lg*8+j]) with 16 VALU ops, deleting the
// 12 LDS ops/wave-step of the P roundtrip. setprio(1) wraps the PV cluster.
__global__ __launch_bounds__(512) void attn_kernel(const u16* __restrict__ Q,
                                                   const u16* __restrict__ Kb,
                                                   const u16* __restrict__ Vt,
                                                   u16* __restrict__ ctx) {
    __shared__ u16 Ks[2][64 * 64];
    __shared__ u16 Vs[2][64 * 64];
#if !HAVE_PERMLANE
    __shared__ u16 Ps[8][2][16][72];
#endif

    const int bh = blockIdx.x;
    const int b = bh >> 4, h = bh & 15;
    const int qb = 7 - (int)blockIdx.y;  // big blocks dispatch first
    const int tid = threadIdx.x, lane = tid & 63, wid = tid >> 6;
    const int l15 = lane & 15, lg = lane >> 4;
    const int q0w = qb * 256 + wid * 32;
    const int send = qb * 256;

    const int rr = tid >> 3, c8 = tid & 7;
    const int scw = (c8 ^ (rr & 7)) * 8;
    const size_t kbase = ((size_t)b * 2048) * 1024 + h * 64 + scw;
    const size_t vbase = ((size_t)bh * 64 + rr) * 2048 + scw;

    f16x8 qv[2][2];
#pragma unroll
    for (int qf = 0; qf < 2; qf++) {
        size_t qoff = ((size_t)b * 2048 + q0w + qf * 16 + l15) * 1024 + h * 64 + lg * 8;
        qv[qf][0] = *(const f16x8*)(Q + qoff);
        qv[qf][1] = *(const f16x8*)(Q + qoff + 32);
    }

    const int swk0 = (lg ^ (l15 & 7)) * 8;
    const int swk1 = ((4 + lg) ^ (l15 & 7)) * 8;
#if !HAVE_PERMLANE
    u16* Pw0 = &Ps[wid][0][0][0] + l15 * 72;
    u16* Pw1 = &Ps[wid][1][0][0] + l15 * 72;
#endif

    const h16x2 one2 = {(__fp16)1.0f, (__fp16)1.0f};

    f32x4 acc[2][4] = {};
    float psum[2] = {0.0f, 0.0f};

    auto stage = [&](int s, int bf) {
        gload16(Kb + kbase + (size_t)(s + rr) * 1024, Ks[bf] + tid * 8);
        gload16(Vt + vbase + s, Vs[bf] + tid * 8);
    };

    auto body = [&](int s, int bf, auto maskc) {
        constexpr bool MASK = decltype(maskc)::v;
        u32 W[2][4][2];  // [qf][c][word] packed fp16 P pairs
#pragma unroll
        for (int c = 0; c < 4; c++) {
            const u16* kp = Ks[bf] + (c * 16 + l15) * 64;
            f16x8 kf0 = *(const f16x8*)(kp + swk0);
            f16x8 kf1 = *(const f16x8*)(kp + swk1);
#pragma unroll
            for (int qf = 0; qf < 2; qf++) {
                f32x4 z = {};
                z = __builtin_amdgcn_mfma_f32_16x16x32_f16(kf0, qv[qf][0], z, 0, 0, 0);
                z = __builtin_amdgcn_mfma_f32_16x16x32_f16(kf1, qv[qf][1], z, 0, 0, 0);
                float p0 = __builtin_amdgcn_exp2f(z[0]);
                float p1 = __builtin_amdgcn_exp2f(z[1]);
                float p2 = __builtin_amdgcn_exp2f(z[2]);
                float p3 = __builtin_amdgcn_exp2f(z[3]);
                if (MASK) {
                    int kk = s + c * 16 + lg * 4;
                    int qq = q0w + qf * 16 + l15;
                    p0 = (kk + 0 <= qq) ? p0 : 0.0f;
                    p1 = (kk + 1 <= qq) ? p1 : 0.0f;
                    p2 = (kk + 2 <= qq) ? p2 : 0.0f;
                    p3 = (kk + 3 <= qq) ? p3 : 0.0f;
                }
                h16x2 w0 = __builtin_amdgcn_cvt_pkrtz(p0, p1);
                h16x2 w1 = __builtin_amdgcn_cvt_pkrtz(p2, p3);
                psum[qf] = __builtin_amdgcn_fdot2(w0, one2, psum[qf], false);
                psum[qf] = __builtin_amdgcn_fdot2(w1, one2, psum[qf], false);
                W[qf][c][0] = __builtin_bit_cast(u32, w0);
                W[qf][c][1] = __builtin_bit_cast(u32, w1);
#if !HAVE_PERMLANE
                uint2 w;
                w.x = W[qf][c][0];
                w.y = W[qf][c][1];
                *(uint2*)((qf ? Pw1 : Pw0) + c * 16 + lg * 4) = w;
#endif
            }
        }
        f16x8 pa0[2], pa1[2];
#if HAVE_PERMLANE
#pragma unroll
        for (int qf = 0; qf < 2; qf++) {
            // pa0: k 0..31 from c-tiles 0,1.  perm32 then perm16:
            //  t[0] = [A@g0, A@g2, B@g0, B@g2]  (word j/2 even slots)
            //  t[1] = [A@g1, A@g3, B@g1, B@g3]
            auto sA = __builtin_amdgcn_permlane32_swap(W[qf][0][0], W[qf][1][0], false, false);
            auto tA = __builtin_amdgcn_permlane16_swap(sA[0], sA[1], false, false);
            auto sB = __builtin_amdgcn_permlane32_swap(W[qf][0][1], W[qf][1][1], false, false);
            auto tB = __builtin_amdgcn_permlane16_swap(sB[0], sB[1], false, false);
            u32x4 v0 = {tA[0], tB[0], tA[1], tB[1]};
            pa0[qf] = __builtin_bit_cast(f16x8, v0);
            auto sC = __builtin_amdgcn_permlane32_swap(W[qf][2][0], W[qf][3][0], false, false);
            auto tC = __builtin_amdgcn_permlane16_swap(sC[0], sC[1], false, false);
            auto sD = __builtin_amdgcn_permlane32_swap(W[qf][2][1], W[qf][3][1], false, false);
            auto tD = __builtin_amdgcn_permlane16_swap(sD[0], sD[1], false, false);
            u32x4 v1 = {tC[0], tD[0], tC[1], tD[1]};
            pa1[qf] = __builtin_bit_cast(f16x8, v1);
        }
#else
#pragma unroll
        for (int qf = 0; qf < 2; qf++) {
            const u16* Pw = qf ? Pw1 : Pw0;
            pa0[qf] = *(const f16x8*)(Pw + lg * 8);
            pa1[qf] = *(const f16x8*)(Pw + 32 + lg * 8);
        }
#endif
        __builtin_amdgcn_s_setprio(1);
#pragma unroll
        for (int dt = 0; dt < 4; dt++) {
            const u16* vp = Vs[bf] + (dt * 16 + l15) * 64;
            f16x8 vf0 = *(const f16x8*)(vp + swk0);
            f16x8 vf1 = *(const f16x8*)(vp + swk1);
#pragma unroll
            for (int qf = 0; qf < 2; qf++) {
                acc[qf][dt] =
                    __builtin_amdgcn_mfma_f32_16x16x32_f16(pa0[qf], vf0, acc[qf][dt], 0, 0, 0);
                acc[qf][dt] =
                    __builtin_amdgcn_mfma_f32_16x16x32_f16(pa1[qf], vf1, acc[qf][dt], 0, 0, 0);
            }
        }
        __builtin_amdgcn_s_setprio(0);
    };

    // prologue: tiles 0 and 64 in flight; wait tile 0 only (vmcnt(2))
    stage(0, 0);
    stage(64, 1);
    asm volatile("s_waitcnt vmcnt(2)" ::: "memory");
    __builtin_amdgcn_sched_barrier(0);
    __builtin_amdgcn_s_barrier();

    int cur = 0;
#pragma unroll 1
    for (int s = 0; s < send; s += 64) {
        body(s, cur, BoolTag<false>{});
        __builtin_amdgcn_sched_barrier(0);
        __builtin_amdgcn_s_barrier();              // all waves done reading cur
        stage(s + 128, cur);                        // overwrite cur with s+128
        asm volatile("s_waitcnt vmcnt(2)" ::: "memory");  // s+64 landed (aged 1 step)
        __builtin_amdgcn_sched_barrier(0);
        __builtin_amdgcn_s_barrier();
        cur ^= 1;
    }
    // diagonal tail: 4 masked steps; wave wid participates iff wid >= 2j.
#pragma unroll 1
    for (int j = 0; j < 4; j++) {
        if (wid >= 2 * j) body(send + 64 * j, cur, BoolTag<true>{});
        __builtin_amdgcn_sched_barrier(0);
        __builtin_amdgcn_s_barrier();
        if (j < 2) {
            stage(send + 64 * (j + 2), cur);
            asm volatile("s_waitcnt vmcnt(2)" ::: "memory");
        } else if (j == 2) {
            asm volatile("s_waitcnt vmcnt(0)" ::: "memory");
        }
        __builtin_amdgcn_sched_barrier(0);
        __builtin_amdgcn_s_barrier();
        cur ^= 1;
    }

#pragma unroll
    for (int qf = 0; qf < 2; qf++) {
        psum[qf] += __shfl_xor(psum[qf], 16);
        psum[qf] += __shfl_xor(psum[qf], 32);
    }
#pragma unroll
    for (int qf = 0; qf < 2; qf++) {
        float inv = 1.0f / psum[qf];
#pragma unroll
        for (int r = 0; r < 4; r++) {
            float ir = __shfl(inv, lg * 4 + r);
            size_t row = (size_t)b * 2048 + q0w + qf * 16 + lg * 4 + r;
#pragma unroll
            for (int dt = 0; dt < 4; dt++)
                ctx[row * 1024 + h * 64 + dt * 16 + l15] = f2h_bits(acc[qf][dt][r] * ir);
        }
    }
}

// -------------------------------------------------------------- layer norm
// y in fp16 (16 MB read vs 32), out f32.
__global__ __launch_bounds__(256) void ln_kernel(const u16* __restrict__ y,
                                                 const float* __restrict__ g,
                                                 const float* __restrict__ bb,
                                                 float* __restrict__ out) {
    const int r = blockIdx.x, tid = threadIdx.x;
    u16x4 v4 = *(const u16x4*)(y + (size_t)r * 1024 + tid * 4);
    float vx = h2f(v4[0]), vy = h2f(v4[1]), vz = h2f(v4[2]), vw = h2f(v4[3]);
    float s = vx + vy + vz + vw;
    float sq = vx * vx + vy * vy + vz * vz + vw * vw;
#pragma unroll
    for (int ofs = 1; ofs < 64; ofs <<= 1) {
        s += __shfl_xor(s, ofs);
        sq += __shfl_xor(sq, ofs);
    }
    __shared__ float as[4], aq[4];
    if ((tid & 63) == 0) { as[tid >> 6] = s; aq[tid >> 6] = sq; }
    __syncthreads();
    s = as[0] + as[1] + as[2] + as[3];
    sq = aq[0] + aq[1] + aq[2] + aq[3];
    float mu = s * (1.0f / 1024.0f);
    float var = sq * (1.0f / 1024.0f) - mu * mu;
    float rstd = rsqrtf(var + 1e-5f);
    float4 gv = *(const float4*)(g + tid * 4);
    float4 bv = *(const float4*)(bb + tid * 4);
    float4 o4;
    o4.x = (vx - mu) * rstd * gv.x + bv.x;
    o4.y = (vy - mu) * rstd * gv.y + bv.y;
    o4.z = (vz - mu) * rstd * gv.z + bv.z;
    o4.w = (vw - mu) * rstd * gv.w + bv.w;
    *(float4*)(out + (size_t)r * 1024 + tid * 4) = o4;
}

// ------------------------------------------------------------------ launch
extern "C" void kernel_launch(void* const* d_in, const int* in_sizes, int n_in,
                              void* d_out, int out_size, void* d_ws, size_t ws_size,
                              hipStream_t stream) {
    const float* x  = (const float*)d_in[0];
    const float* Wq = (const float*)d_in[1];
    const float* bq = (const float*)d_in[2];
    const float* Wk = (const float*)d_in[3];
    const float* bk = (const float*)d_in[4];
    const float* Wv = (const float*)d_in[5];
    const float* bv = (const float*)d_in[6];
    const float* Wo = (const float*)d_in[7];
    const float* bo = (const float*)d_in[8];
    const float* lg = (const float*)d_in[9];
    const float* lb = (const float*)d_in[10];
    float* out = (float*)d_out;

    char* ws = (char*)d_ws;
    u16* xb = (u16*)(ws + 0);
    u16* wt = (u16*)(ws + 16777216);
    u16* q  = (u16*)(ws + 25165824);
    u16* k  = (u16*)(ws + 41943040);
    u16* vt = (u16*)(ws + 75497472);
    u16* cx = (u16*)(ws + 92274688);
    u16* y16 = (u16*)(ws + 109051904);

    convert_kernel<<<5120, 256, 0, stream>>>(x, xb, Wq, Wk, Wv, Wo, wt);

    gemm256_kernel<0><<<768, 512, 0, stream>>>(xb, wt, bq, bk, bv, q, k, vt);
    attn_kernel<<<dim3(64, 8), 512, 0, stream>>>(q, k, vt, cx);
    gemm256_kernel<1><<<256, 512, 0, stream>>>(cx, wt + 3145728, bo, nullptr,
                                               nullptr, y16, xb, nullptr);
    ln_kernel<<<8192, 256, 0, stream>>>(y16, lg, lb, out);
}

// Round 17
// 170.439 us; speedup vs baseline: 1.1534x; 1.0035x over previous
//
#include <hip/hip_runtime.h>

// Problem constants: B=4, T=2048, D=1024, H=16, DK=64, M = B*T = 8192.
// Workspace layout (bytes):
//   xb  @ 0         : x as fp16            (16 MB)   (also residual source)
//   wt  @ 16 MB     : Wq,Wk,Wv,Wo transposed [N][K] fp16 (4 x 2 MB)
//   q   @ 24 MB     : Q (pre-scaled by log2e/8) [B*T, D] fp16 (16 MB)
//   k   @ 40 MB     : K  [B*T, D] fp16     (16 MB)
//   vt  @ 72 MB     : V^T [B*H][64][T] fp16(16 MB)  <- written by QKV epilogue
//   cx  @ 88 MB     : attention ctx fp16   (16 MB)
//   y   @ 104 MB    : pre-LN fp16          (16 MB)

using u16 = unsigned short;
using u32 = unsigned int;
typedef _Float16 f16x8 __attribute__((ext_vector_type(8)));
typedef __fp16 h16x2 __attribute__((ext_vector_type(2)));   // cvt_pkrtz/fdot2 type
typedef float f32x4 __attribute__((ext_vector_type(4)));
typedef unsigned short u16x8 __attribute__((ext_vector_type(8)));
typedef unsigned short u16x4 __attribute__((ext_vector_type(4)));
typedef unsigned int u32x4 __attribute__((ext_vector_type(4)));

#if __has_builtin(__builtin_amdgcn_permlane16_swap) && \
    __has_builtin(__builtin_amdgcn_permlane32_swap)
#define HAVE_PERMLANE 1
#else
#define HAVE_PERMLANE 0
#endif

template <bool B> struct BoolTag { static constexpr bool v = B; };

__device__ inline u16 f2h_bits(float f) {
    _Float16 h = (_Float16)f;
    return __builtin_bit_cast(u16, h);
}
__device__ inline float h2f(u16 u) {
    return (float)__builtin_bit_cast(_Float16, u);
}

__device__ __forceinline__ void gload16(const void* g, void* l) {
    __builtin_amdgcn_global_load_lds(
        (const __attribute__((address_space(1))) void*)g,
        (__attribute__((address_space(3))) void*)l, 16, 0, 0);
}

// -------------------------- fused converts: x -> fp16, W^T x4 -> fp16
// blocks 0..4095: x;  blocks 4096..5119: weight tiles (z = wb>>8).
__global__ __launch_bounds__(256) void convert_kernel(
    const float* __restrict__ x, u16* __restrict__ xb,
    const float* __restrict__ W0, const float* __restrict__ W1,
    const float* __restrict__ W2, const float* __restrict__ W3,
    u16* __restrict__ Wt) {
    __shared__ float ts[64][68];
    const int bid = blockIdx.x, tid = threadIdx.x;
    if (bid < 4096) {
        size_t i = ((size_t)bid * 256 + tid) * 8;
        float4 a = *(const float4*)(x + i);
        float4 b = *(const float4*)(x + i + 4);
        u16x8 o;
        o[0] = f2h_bits(a.x); o[1] = f2h_bits(a.y); o[2] = f2h_bits(a.z); o[3] = f2h_bits(a.w);
        o[4] = f2h_bits(b.x); o[5] = f2h_bits(b.y); o[6] = f2h_bits(b.z); o[7] = f2h_bits(b.w);
        *(u16x8*)(xb + i) = o;
        return;
    }
    const int wb = bid - 4096;
    const int z = wb >> 8, rem = wb & 255;
    const float* W = z == 0 ? W0 : (z == 1 ? W1 : (z == 2 ? W2 : W3));
    u16* Wo = Wt + (size_t)z * 1048576;
    const int k0 = (rem >> 4) * 64, n0 = (rem & 15) * 64;
    const int rr = tid >> 3, c = tid & 7;
#pragma unroll
    for (int p = 0; p < 2; p++) {
        int k = p * 32 + rr;
        float4 u = *(const float4*)(W + (size_t)(k0 + k) * 1024 + n0 + c * 8);
        float4 w = *(const float4*)(W + (size_t)(k0 + k) * 1024 + n0 + c * 8 + 4);
        *(float4*)&ts[k][c * 8] = u;
        *(float4*)&ts[k][c * 8 + 4] = w;
    }
    __syncthreads();
#pragma unroll
    for (int p = 0; p < 2; p++) {
        int n = p * 32 + rr;
        u16 o[8];
#pragma unroll
        for (int j = 0; j < 8; j++) o[j] = f2h_bits(ts[c * 8 + j][n]);
        *(u16x8*)(Wo + (size_t)(n0 + n) * 1024 + k0 + c * 8) = *(u16x8*)o;
    }
}

// --------------------------------------------------------- 128x256 GEMM
// C[M,N] = A[M,1024] @ W (W as Wt[N][1024] fp16). BM=128, BN=256, BK=64.
// 512 threads = 8 waves (2M x 4N), per-wave 64x64. Triple-buffered LDS,
// m201-style phases, counted vmcnt(6) per K-tile.
// MODE 0: QKV fused (N=3072): Q/K fp16 out + bias (+log2e/8 scale on Q);
//         V blocks transpose in-LDS (stride 134) and write vt directly.
// MODE 1: Wo: y16 = fp16(acc + bias + residual_fp16); qo=y16 out, ko=xb.
template <int MODE>
__global__ __launch_bounds__(512) void gemm256_kernel(
    const u16* __restrict__ A, const u16* __restrict__ Wt,
    const float* __restrict__ b0, const float* __restrict__ b1,
    const float* __restrict__ b2, u16* __restrict__ qo, u16* __restrict__ ko,
    u16* __restrict__ vt) {
    constexpr int NBY = (MODE == 0) ? 12 : 4;
    __shared__ u16 As[3][128 * 64];
    __shared__ u16 Bs[3][256 * 64];

    const int bid = blockIdx.x;
    const int cpx = (MODE == 0) ? 96 : 32;        // gridDim/8, grid%8==0
    const int swz = (bid & 7) * cpx + (bid >> 3); // XCD-contiguous
    const int bx = swz / NBY, by = swz % NBY;
    const size_t row0 = (size_t)bx * 128;
    const size_t col0 = (size_t)by * 256;

    const int tid = threadIdx.x, lane = tid & 63;
    const int wid = tid >> 6, wm = wid >> 2, wn = wid & 3;
    const int l15 = lane & 15, lg = lane >> 4;
    const int rr = tid >> 3, c8 = tid & 7;
    const int scw = (c8 ^ (rr & 7)) * 8;          // pre-swizzled source chunk

    f32x4 acc[4][4] = {};

    auto stage_half = [&](int kt, u16* dA, u16* dB, int h) {
        const int k0 = kt * 64;
        if (h == 0) {
            gload16(A + (row0 + rr) * 1024 + k0 + scw, dA + tid * 8);
            gload16(Wt + (col0 + rr) * 1024 + k0 + scw, dB + tid * 8);
            gload16(Wt + (col0 + 64 + rr) * 1024 + k0 + scw, dB + (512 + tid) * 8);
        } else {
            gload16(A + (row0 + 64 + rr) * 1024 + k0 + scw, dA + (512 + tid) * 8);
            gload16(Wt + (col0 + 128 + rr) * 1024 + k0 + scw, dB + (1024 + tid) * 8);
            gload16(Wt + (col0 + 192 + rr) * 1024 + k0 + scw, dB + (1536 + tid) * 8);
        }
    };

    auto ldops = [&](const u16* bA, const u16* bB, int kcv, f16x8* Af, f16x8* Bf) {
        const int swo = ((kcv * 4 + lg) ^ (l15 & 7)) * 8;
#pragma unroll
        for (int n = 0; n < 4; n++)
            Bf[n] = *(const f16x8*)(bB + (wn * 64 + n * 16 + l15) * 64 + swo);
#pragma unroll
        for (int m = 0; m < 4; m++)
            Af[m] = *(const f16x8*)(bA + (wm * 64 + m * 16 + l15) * 64 + swo);
    };

    auto domfma = [&](const f16x8* Af, const f16x8* Bf) {
        __builtin_amdgcn_s_setprio(1);
#pragma unroll
        for (int m = 0; m < 4; m++)
#pragma unroll
            for (int n = 0; n < 4; n++)
                acc[m][n] = __builtin_amdgcn_mfma_f32_16x16x32_f16(
                    Af[m], Bf[n], acc[m][n], 0, 0, 0);
        __builtin_amdgcn_s_setprio(0);
    };

    u16 *pA = &As[0][0], *pnA = &As[1][0], *ppA = &As[2][0];
    u16 *pB = &Bs[0][0], *pnB = &Bs[1][0], *ppB = &Bs[2][0];

    stage_half(0, pA, pB, 0);
    stage_half(0, pA, pB, 1);
    stage_half(1, pnA, pnB, 0);
    stage_half(1, pnA, pnB, 1);
    asm volatile("s_waitcnt vmcnt(6)" ::: "memory");
    __builtin_amdgcn_sched_barrier(0);
    __builtin_amdgcn_s_barrier();

#pragma unroll 1
    for (int t = 0; t < 16; t++) {
        f16x8 af[4], bf[4];
        ldops(pA, pB, 0, af, bf);
        if (t < 14) stage_half(t + 2, ppA, ppB, 0);
        __builtin_amdgcn_sched_barrier(0);
        __builtin_amdgcn_s_barrier();
        asm volatile("s_waitcnt lgkmcnt(0)" ::: "memory");
        __builtin_amdgcn_sched_barrier(0);
        domfma(af, bf);
        __builtin_amdgcn_sched_barrier(0);
        __builtin_amdgcn_s_barrier();
        ldops(pA, pB, 1, af, bf);
        if (t < 14) stage_half(t + 2, ppA, ppB, 1);
        if (t < 14)       asm volatile("s_waitcnt vmcnt(6)" ::: "memory");
        else if (t == 14) asm volatile("s_waitcnt vmcnt(0)" ::: "memory");
        __builtin_amdgcn_sched_barrier(0);
        __builtin_amdgcn_s_barrier();
        asm volatile("s_waitcnt lgkmcnt(0)" ::: "memory");
        __builtin_amdgcn_sched_barrier(0);
        domfma(af, bf);
        __builtin_amdgcn_sched_barrier(0);
        if (t < 15) {
            __builtin_amdgcn_s_barrier();
            u16* tp;
            tp = pA; pA = pnA; pnA = ppA; ppA = tp;
            tp = pB; pB = pnB; pnB = ppB; ppB = tp;
        }
    }

    if (MODE == 0) {
        const int zsel = by >> 2;  // 0=Q, 1=K, 2=V
        if (zsel < 2) {
            u16* ob = zsel == 0 ? qo : ko;
            const float* bias = zsel == 0 ? b0 : b1;
            const float qs = zsel == 0 ? 0.18033688f : 1.0f;  // log2(e)/8 on Q
#pragma unroll
            for (int m = 0; m < 4; m++) {
#pragma unroll
                for (int n = 0; n < 4; n++) {
                    size_t col = col0 + wn * 64 + n * 16 + l15;
                    size_t colz = col & 1023;
                    float bb = bias[colz];
#pragma unroll
                    for (int r = 0; r < 4; r++) {
                        size_t row = row0 + wm * 64 + m * 16 + lg * 4 + r;
                        ob[row * 1024 + colz] = f2h_bits((acc[m][n][r] + bb) * qs);
                    }
                }
            }
        } else {
            // V: bias + in-LDS transpose -> vt[(b*16+h)*64+d][t]
            u16* TL = &Bs[0][0];  // [256][134] u16 = 68608 B (Bs is 98304 B)
            __syncthreads();
#pragma unroll
            for (int m = 0; m < 4; m++) {
#pragma unroll
                for (int n = 0; n < 4; n++) {
                    int cl = wn * 64 + n * 16 + l15;
                    float bb = b2[(col0 & 1023) + cl];
#pragma unroll
                    for (int r = 0; r < 4; r++) {
                        int rl = wm * 64 + m * 16 + lg * 4 + r;
                        TL[cl * 134 + rl] = f2h_bits(acc[m][n][r] + bb);
                    }
                }
            }
            __syncthreads();
            const int vrl = tid >> 1, th = tid & 1;
            size_t vrow = (row0 >> 11) * 1024 + (col0 & 1023) + vrl;
            const int t0loc = (int)(row0 & 2047) + th * 64;
#pragma unroll
            for (int j = 0; j < 8; j++)
                *(u16x8*)(vt + vrow * 2048 + t0loc + j * 8) =
                    *(const u16x8*)(TL + vrl * 134 + th * 64 + j * 8);
        }
    } else {
        // Wo: y16 = fp16(acc + bias + fp16 residual from xb)
        u16* yo = qo;
        const u16* xres = ko;
#pragma unroll
        for (int m = 0; m < 4; m++) {
#pragma unroll
            for (int n = 0; n < 4; n++) {
                size_t col = col0 + wn * 64 + n * 16 + l15;
                float bb = b0[col];
#pragma unroll
                for (int r = 0; r < 4; r++) {
                    size_t row = row0 + wm * 64 + m * 16 + lg * 4 + r;
                    size_t idx = row * 1024 + col;
                    yo[idx] = f2h_bits(acc[m][n][r] + bb + h2f(xres[idx]));
                }
            }
        }
    }
}

// ------------------------------------------------------------ attention v11
// 8 waves x 32 q = 256 q/block, KV steps of 64, 1D grid of 512 blocks with
// ANTI-CORRELATED qb pairing: blocks 0..255 carry qb in {7,6,5,4}, blocks
// 256..511 carry qb in {0,1,2,3}, so the co-resident pair (i, i+256) on each
// CU always sums to 7 -> uniform 36-step path per CU (was 48 worst-case).
// Counted-vmcnt K/V pipeline; T12 permlane P redistribution; setprio on PV.
__global__ __launch_bounds__(512) void attn_kernel(const u16* __restrict__ Q,
                                                   const u16* __restrict__ Kb,
                                                   const u16* __restrict__ Vt,
                                                   u16* __restrict__ ctx) {
    __shared__ u16 Ks[2][64 * 64];
    __shared__ u16 Vs[2][64 * 64];
#if !HAVE_PERMLANE
    __shared__ u16 Ps[8][2][16][72];
#endif

    const int i = (int)blockIdx.x;
    const int bh = i & 63;
    const int sel = (i >> 6) & 3;
    const int qb = (i < 256) ? (7 - sel) : sel;   // pair (i, i+256) sums to 7
    const int b = bh >> 4, h = bh & 15;
    const int tid = threadIdx.x, lane = tid & 63, wid = tid >> 6;
    const int l15 = lane & 15, lg = lane >> 4;
    const int q0w = qb * 256 + wid * 32;
    const int send = qb * 256;

    const int rr = tid >> 3, c8 = tid & 7;
    const int scw = (c8 ^ (rr & 7)) * 8;
    const size_t kbase = ((size_t)b * 2048) * 1024 + h * 64 + scw;
    const size_t vbase = ((size_t)bh * 64 + rr) * 2048 + scw;

    f16x8 qv[2][2];
#pragma unroll
    for (int qf = 0; qf < 2; qf++) {
        size_t qoff = ((size_t)b * 2048 + q0w + qf * 16 + l15) * 1024 + h * 64 + lg * 8;
        qv[qf][0] = *(const f16x8*)(Q + qoff);
        qv[qf][1] = *(const f16x8*)(Q + qoff + 32);
    }

    const int swk0 = (lg ^ (l15 & 7)) * 8;
    const int swk1 = ((4 + lg) ^ (l15 & 7)) * 8;
#if !HAVE_PERMLANE
    u16* Pw0 = &Ps[wid][0][0][0] + l15 * 72;
    u16* Pw1 = &Ps[wid][1][0][0] + l15 * 72;
#endif

    const h16x2 one2 = {(__fp16)1.0f, (__fp16)1.0f};

    f32x4 acc[2][4] = {};
    float psum[2] = {0.0f, 0.0f};

    auto stage = [&](int s, int bf) {
        gload16(Kb + kbase + (size_t)(s + rr) * 1024, Ks[bf] + tid * 8);
        gload16(Vt + vbase + s, Vs[bf] + tid * 8);
    };

    auto body = [&](int s, int bf, auto maskc) {
        constexpr bool MASK = decltype(maskc)::v;
        u32 W[2][4][2];  // [qf][c][word] packed fp16 P pairs
#pragma unroll
        for (int c = 0; c < 4; c++) {
            const u16* kp = Ks[bf] + (c * 16 + l15) * 64;
            f16x8 kf0 = *(const f16x8*)(kp + swk0);
            f16x8 kf1 = *(const f16x8*)(kp + swk1);
#pragma unroll
            for (int qf = 0; qf < 2; qf++) {
                f32x4 z = {};
                z = __builtin_amdgcn_mfma_f32_16x16x32_f16(kf0, qv[qf][0], z, 0, 0, 0);
                z = __builtin_amdgcn_mfma_f32_16x16x32_f16(kf1, qv[qf][1], z, 0, 0, 0);
                float p0 = __builtin_amdgcn_exp2f(z[0]);
                float p1 = __builtin_amdgcn_exp2f(z[1]);
                float p2 = __builtin_amdgcn_exp2f(z[2]);
                float p3 = __builtin_amdgcn_exp2f(z[3]);
                if (MASK) {
                    int kk = s + c * 16 + lg * 4;
                    int qq = q0w + qf * 16 + l15;
                    p0 = (kk + 0 <= qq) ? p0 : 0.0f;
                    p1 = (kk + 1 <= qq) ? p1 : 0.0f;
                    p2 = (kk + 2 <= qq) ? p2 : 0.0f;
                    p3 = (kk + 3 <= qq) ? p3 : 0.0f;
                }
                h16x2 w0 = __builtin_amdgcn_cvt_pkrtz(p0, p1);
                h16x2 w1 = __builtin_amdgcn_cvt_pkrtz(p2, p3);
                psum[qf] = __builtin_amdgcn_fdot2(w0, one2, psum[qf], false);
                psum[qf] = __builtin_amdgcn_fdot2(w1, one2, psum[qf], false);
                W[qf][c][0] = __builtin_bit_cast(u32, w0);
                W[qf][c][1] = __builtin_bit_cast(u32, w1);
#if !HAVE_PERMLANE
                uint2 w;
                w.x = W[qf][c][0];
                w.y = W[qf][c][1];
                *(uint2*)((qf ? Pw1 : Pw0) + c * 16 + lg * 4) = w;
#endif
            }
        }
        f16x8 pa0[2], pa1[2];
#if HAVE_PERMLANE
#pragma unroll
        for (int qf = 0; qf < 2; qf++) {
            auto sA = __builtin_amdgcn_permlane32_swap(W[qf][0][0], W[qf][1][0], false, false);
            auto tA = __builtin_amdgcn_permlane16_swap(sA[0], sA[1], false, false);
            auto sB = __builtin_amdgcn_permlane32_swap(W[qf][0][1], W[qf][1][1], false, false);
            auto tB = __builtin_amdgcn_permlane16_swap(sB[0], sB[1], false, false);
            u32x4 v0 = {tA[0], tB[0], tA[1], tB[1]};
            pa0[qf] = __builtin_bit_cast(f16x8, v0);
            auto sC = __builtin_amdgcn_permlane32_swap(W[qf][2][0], W[qf][3][0], false, false);
            auto tC = __builtin_amdgcn_permlane16_swap(sC[0], sC[1], false, false);
            auto sD = __builtin_amdgcn_permlane32_swap(W[qf][2][1], W[qf][3][1], false, false);
            auto tD = __builtin_amdgcn_permlane16_swap(sD[0], sD[1], false, false);
            u32x4 v1 = {tC[0], tD[0], tC[1], tD[1]};
            pa1[qf] = __builtin_bit_cast(f16x8, v1);
        }
#else
#pragma unroll
        for (int qf = 0; qf < 2; qf++) {
            const u16* Pw = qf ? Pw1 : Pw0;
            pa0[qf] = *(const f16x8*)(Pw + lg * 8);
            pa1[qf] = *(const f16x8*)(Pw + 32 + lg * 8);
        }
#endif
        __builtin_amdgcn_s_setprio(1);
#pragma unroll
        for (int dt = 0; dt < 4; dt++) {
            const u16* vp = Vs[bf] + (dt * 16 + l15) * 64;
            f16x8 vf0 = *(const f16x8*)(vp + swk0);
            f16x8 vf1 = *(const f16x8*)(vp + swk1);
#pragma unroll
            for (int qf = 0; qf < 2; qf++) {
                acc[qf][dt] =
                    __builtin_amdgcn_mfma_f32_16x16x32_f16(pa0[qf], vf0, acc[qf][dt], 0, 0, 0);
                acc[qf][dt] =
                    __builtin_amdgcn_mfma_f32_16x16x32_f16(pa1[qf], vf1, acc[qf][dt], 0, 0, 0);
            }
        }
        __builtin_amdgcn_s_setprio(0);
    };

    // prologue: tiles 0 and 64 in flight; wait tile 0 only (vmcnt(2))
    stage(0, 0);
    stage(64, 1);
    asm volatile("s_waitcnt vmcnt(2)" ::: "memory");
    __builtin_amdgcn_sched_barrier(0);
    __builtin_amdgcn_s_barrier();

    int cur = 0;
#pragma unroll 1
    for (int s = 0; s < send; s += 64) {
        body(s, cur, BoolTag<false>{});
        __builtin_amdgcn_sched_barrier(0);
        __builtin_amdgcn_s_barrier();              // all waves done reading cur
        stage(s + 128, cur);                        // overwrite cur with s+128
        asm volatile("s_waitcnt vmcnt(2)" ::: "memory");  // s+64 landed (aged 1 step)
        __builtin_amdgcn_sched_barrier(0);
        __builtin_amdgcn_s_barrier();
        cur ^= 1;
    }
    // diagonal tail: 4 masked steps; wave wid participates iff wid >= 2j.
#pragma unroll 1
    for (int j = 0; j < 4; j++) {
        if (wid >= 2 * j) body(send + 64 * j, cur, BoolTag<true>{});
        __builtin_amdgcn_sched_barrier(0);
        __builtin_amdgcn_s_barrier();
        if (j < 2) {
            stage(send + 64 * (j + 2), cur);
            asm volatile("s_waitcnt vmcnt(2)" ::: "memory");
        } else if (j == 2) {
            asm volatile("s_waitcnt vmcnt(0)" ::: "memory");
        }
        __builtin_amdgcn_sched_barrier(0);
        __builtin_amdgcn_s_barrier();
        cur ^= 1;
    }

#pragma unroll
    for (int qf = 0; qf < 2; qf++) {
        psum[qf] += __shfl_xor(psum[qf], 16);
        psum[qf] += __shfl_xor(psum[qf], 32);
    }
#pragma unroll
    for (int qf = 0; qf < 2; qf++) {
        float inv = 1.0f / psum[qf];
#pragma unroll
        for (int r = 0; r < 4; r++) {
            float ir = __shfl(inv, lg * 4 + r);
            size_t row = (size_t)b * 2048 + q0w + qf * 16 + lg * 4 + r;
#pragma unroll
            for (int dt = 0; dt < 4; dt++)
                ctx[row * 1024 + h * 64 + dt * 16 + l15] = f2h_bits(acc[qf][dt][r] * ir);
        }
    }
}

// -------------------------------------------------------------- layer norm
// y in fp16 (16 MB read vs 32), out f32.
__global__ __launch_bounds__(256) void ln_kernel(const u16* __restrict__ y,
                                                 const float* __restrict__ g,
                                                 const float* __restrict__ bb,
                                                 float* __restrict__ out) {
    const int r = blockIdx.x, tid = threadIdx.x;
    u16x4 v4 = *(const u16x4*)(y + (size_t)r * 1024 + tid * 4);
    float vx = h2f(v4[0]), vy = h2f(v4[1]), vz = h2f(v4[2]), vw = h2f(v4[3]);
    float s = vx + vy + vz + vw;
    float sq = vx * vx + vy * vy + vz * vz + vw * vw;
#pragma unroll
    for (int ofs = 1; ofs < 64; ofs <<= 1) {
        s += __shfl_xor(s, ofs);
        sq += __shfl_xor(sq, ofs);
    }
    __shared__ float as[4], aq[4];
    if ((tid & 63) == 0) { as[tid >> 6] = s; aq[tid >> 6] = sq; }
    __syncthreads();
    s = as[0] + as[1] + as[2] + as[3];
    sq = aq[0] + aq[1] + aq[2] + aq[3];
    float mu = s * (1.0f / 1024.0f);
    float var = sq * (1.0f / 1024.0f) - mu * mu;
    float rstd = rsqrtf(var + 1e-5f);
    float4 gv = *(const float4*)(g + tid * 4);
    float4 bv = *(const float4*)(bb + tid * 4);
    float4 o4;
    o4.x = (vx - mu) * rstd * gv.x + bv.x;
    o4.y = (vy - mu) * rstd * gv.y + bv.y;
    o4.z = (vz - mu) * rstd * gv.z + bv.z;
    o4.w = (vw - mu) * rstd * gv.w + bv.w;
    *(float4*)(out + (size_t)r * 1024 + tid * 4) = o4;
}

// ------------------------------------------------------------------ launch
extern "C" void kernel_launch(void* const* d_in, const int* in_sizes, int n_in,
                              void* d_out, int out_size, void* d_ws, size_t ws_size,
                              hipStream_t stream) {
    const float* x  = (const float*)d_in[0];
    const float* Wq = (const float*)d_in[1];
    const float* bq = (const float*)d_in[2];
    const float* Wk = (const float*)d_in[3];
    const float* bk = (const float*)d_in[4];
    const float* Wv = (const float*)d_in[5];
    const float* bv = (const float*)d_in[6];
    const float* Wo = (const float*)d_in[7];
    const float* bo = (const float*)d_in[8];
    const float* lg = (const float*)d_in[9];
    const float* lb = (const float*)d_in[10];
    float* out = (float*)d_out;

    char* ws = (char*)d_ws;
    u16* xb = (u16*)(ws + 0);
    u16* wt = (u16*)(ws + 16777216);
    u16* q  = (u16*)(ws + 25165824);
    u16* k  = (u16*)(ws + 41943040);
    u16* vt = (u16*)(ws + 75497472);
    u16* cx = (u16*)(ws + 92274688);
    u16* y16 = (u16*)(ws + 109051904);

    convert_kernel<<<5120, 256, 0, stream>>>(x, xb, Wq, Wk, Wv, Wo, wt);

    gemm256_kernel<0><<<768, 512, 0, stream>>>(xb, wt, bq, bk, bv, q, k, vt);
    attn_kernel<<<512, 512, 0, stream>>>(q, k, vt, cx);
    gemm256_kernel<1><<<256, 512, 0, stream>>>(cx, wt + 3145728, bo, nullptr,
                                               nullptr, y16, xb, nullptr);
    ln_kernel<<<8192, 256, 0, stream>>>(y16, lg, lb, out);
}

// Round 18
// 166.714 us; speedup vs baseline: 1.1791x; 1.0223x over previous
//
#include <hip/hip_runtime.h>

// Problem constants: B=4, T=2048, D=1024, H=16, DK=64, M = B*T = 8192.
// Workspace layout (bytes):
//   xb  @ 0         : x as fp16            (16 MB)   (also residual source)
//   wt  @ 16 MB     : Wq,Wk,Wv,Wo transposed [N][K] fp16 (4 x 2 MB)
//   q   @ 24 MB     : Q (pre-scaled by log2e/8) [B*T, D] fp16 (16 MB)
//   k   @ 40 MB     : K  [B*T, D] fp16     (16 MB)
//   vt  @ 72 MB     : V^T [B*H][64][T] fp16(16 MB)  <- written by QKV epilogue
//   cx  @ 88 MB     : attention ctx fp16   (16 MB)
//   y   @ 104 MB    : pre-LN fp16          (16 MB)

using u16 = unsigned short;
using u32 = unsigned int;
typedef _Float16 f16x8 __attribute__((ext_vector_type(8)));
typedef __fp16 h16x2 __attribute__((ext_vector_type(2)));   // cvt_pkrtz/fdot2 type
typedef float f32x4 __attribute__((ext_vector_type(4)));
typedef unsigned short u16x8 __attribute__((ext_vector_type(8)));
typedef unsigned short u16x4 __attribute__((ext_vector_type(4)));
typedef unsigned int u32x4 __attribute__((ext_vector_type(4)));

template <bool B> struct BoolTag { static constexpr bool v = B; };

__device__ inline u16 f2h_bits(float f) {
    _Float16 h = (_Float16)f;
    return __builtin_bit_cast(u16, h);
}
__device__ inline float h2f(u16 u) {
    return (float)__builtin_bit_cast(_Float16, u);
}

__device__ __forceinline__ void gload16(const void* g, void* l) {
    __builtin_amdgcn_global_load_lds(
        (const __attribute__((address_space(1))) void*)g,
        (__attribute__((address_space(3))) void*)l, 16, 0, 0);
}

// -------------------------- fused converts: x -> fp16, W^T x4 -> fp16
// blocks 0..4095: x;  blocks 4096..5119: weight tiles (z = wb>>8).
__global__ __launch_bounds__(256) void convert_kernel(
    const float* __restrict__ x, u16* __restrict__ xb,
    const float* __restrict__ W0, const float* __restrict__ W1,
    const float* __restrict__ W2, const float* __restrict__ W3,
    u16* __restrict__ Wt) {
    __shared__ float ts[64][68];
    const int bid = blockIdx.x, tid = threadIdx.x;
    if (bid < 4096) {
        size_t i = ((size_t)bid * 256 + tid) * 8;
        float4 a = *(const float4*)(x + i);
        float4 b = *(const float4*)(x + i + 4);
        u16x8 o;
        o[0] = f2h_bits(a.x); o[1] = f2h_bits(a.y); o[2] = f2h_bits(a.z); o[3] = f2h_bits(a.w);
        o[4] = f2h_bits(b.x); o[5] = f2h_bits(b.y); o[6] = f2h_bits(b.z); o[7] = f2h_bits(b.w);
        *(u16x8*)(xb + i) = o;
        return;
    }
    const int wb = bid - 4096;
    const int z = wb >> 8, rem = wb & 255;
    const float* W = z == 0 ? W0 : (z == 1 ? W1 : (z == 2 ? W2 : W3));
    u16* Wo = Wt + (size_t)z * 1048576;
    const int k0 = (rem >> 4) * 64, n0 = (rem & 15) * 64;
    const int rr = tid >> 3, c = tid & 7;
#pragma unroll
    for (int p = 0; p < 2; p++) {
        int k = p * 32 + rr;
        float4 u = *(const float4*)(W + (size_t)(k0 + k) * 1024 + n0 + c * 8);
        float4 w = *(const float4*)(W + (size_t)(k0 + k) * 1024 + n0 + c * 8 + 4);
        *(float4*)&ts[k][c * 8] = u;
        *(float4*)&ts[k][c * 8 + 4] = w;
    }
    __syncthreads();
#pragma unroll
    for (int p = 0; p < 2; p++) {
        int n = p * 32 + rr;
        u16 o[8];
#pragma unroll
        for (int j = 0; j < 8; j++) o[j] = f2h_bits(ts[c * 8 + j][n]);
        *(u16x8*)(Wo + (size_t)(n0 + n) * 1024 + k0 + c * 8) = *(u16x8*)o;
    }
}

// --------------------------------------------------------- 128x256 GEMM
// C[M,N] = A[M,1024] @ W (W as Wt[N][1024] fp16). BM=128, BN=256, BK=64.
// 512 threads = 8 waves (2M x 4N), per-wave 64x64. Triple-buffered LDS,
// m201-style phases, counted vmcnt(6) per K-tile.
// MODE 0: QKV fused (N=3072): Q/K fp16 out + bias (+log2e/8 scale on Q);
//         V blocks transpose in-LDS (stride 134) and write vt directly.
// MODE 1: Wo: y16 = fp16(acc + bias + residual_fp16); qo=y16 out, ko=xb.
template <int MODE>
__global__ __launch_bounds__(512) void gemm256_kernel(
    const u16* __restrict__ A, const u16* __restrict__ Wt,
    const float* __restrict__ b0, const float* __restrict__ b1,
    const float* __restrict__ b2, u16* __restrict__ qo, u16* __restrict__ ko,
    u16* __restrict__ vt) {
    constexpr int NBY = (MODE == 0) ? 12 : 4;
    __shared__ u16 As[3][128 * 64];
    __shared__ u16 Bs[3][256 * 64];

    const int bid = blockIdx.x;
    const int cpx = (MODE == 0) ? 96 : 32;        // gridDim/8, grid%8==0
    const int swz = (bid & 7) * cpx + (bid >> 3); // XCD-contiguous
    const int bx = swz / NBY, by = swz % NBY;
    const size_t row0 = (size_t)bx * 128;
    const size_t col0 = (size_t)by * 256;

    const int tid = threadIdx.x, lane = tid & 63;
    const int wid = tid >> 6, wm = wid >> 2, wn = wid & 3;
    const int l15 = lane & 15, lg = lane >> 4;
    const int rr = tid >> 3, c8 = tid & 7;
    const int scw = (c8 ^ (rr & 7)) * 8;          // pre-swizzled source chunk

    f32x4 acc[4][4] = {};

    auto stage_half = [&](int kt, u16* dA, u16* dB, int h) {
        const int k0 = kt * 64;
        if (h == 0) {
            gload16(A + (row0 + rr) * 1024 + k0 + scw, dA + tid * 8);
            gload16(Wt + (col0 + rr) * 1024 + k0 + scw, dB + tid * 8);
            gload16(Wt + (col0 + 64 + rr) * 1024 + k0 + scw, dB + (512 + tid) * 8);
        } else {
            gload16(A + (row0 + 64 + rr) * 1024 + k0 + scw, dA + (512 + tid) * 8);
            gload16(Wt + (col0 + 128 + rr) * 1024 + k0 + scw, dB + (1024 + tid) * 8);
            gload16(Wt + (col0 + 192 + rr) * 1024 + k0 + scw, dB + (1536 + tid) * 8);
        }
    };

    auto ldops = [&](const u16* bA, const u16* bB, int kcv, f16x8* Af, f16x8* Bf) {
        const int swo = ((kcv * 4 + lg) ^ (l15 & 7)) * 8;
#pragma unroll
        for (int n = 0; n < 4; n++)
            Bf[n] = *(const f16x8*)(bB + (wn * 64 + n * 16 + l15) * 64 + swo);
#pragma unroll
        for (int m = 0; m < 4; m++)
            Af[m] = *(const f16x8*)(bA + (wm * 64 + m * 16 + l15) * 64 + swo);
    };

    auto domfma = [&](const f16x8* Af, const f16x8* Bf) {
        __builtin_amdgcn_s_setprio(1);
#pragma unroll
        for (int m = 0; m < 4; m++)
#pragma unroll
            for (int n = 0; n < 4; n++)
                acc[m][n] = __builtin_amdgcn_mfma_f32_16x16x32_f16(
                    Af[m], Bf[n], acc[m][n], 0, 0, 0);
        __builtin_amdgcn_s_setprio(0);
    };

    u16 *pA = &As[0][0], *pnA = &As[1][0], *ppA = &As[2][0];
    u16 *pB = &Bs[0][0], *pnB = &Bs[1][0], *ppB = &Bs[2][0];

    stage_half(0, pA, pB, 0);
    stage_half(0, pA, pB, 1);
    stage_half(1, pnA, pnB, 0);
    stage_half(1, pnA, pnB, 1);
    asm volatile("s_waitcnt vmcnt(6)" ::: "memory");
    __builtin_amdgcn_sched_barrier(0);
    __builtin_amdgcn_s_barrier();

#pragma unroll 1
    for (int t = 0; t < 16; t++) {
        f16x8 af[4], bf[4];
        ldops(pA, pB, 0, af, bf);
        if (t < 14) stage_half(t + 2, ppA, ppB, 0);
        __builtin_amdgcn_sched_barrier(0);
        __builtin_amdgcn_s_barrier();
        asm volatile("s_waitcnt lgkmcnt(0)" ::: "memory");
        __builtin_amdgcn_sched_barrier(0);
        domfma(af, bf);
        __builtin_amdgcn_sched_barrier(0);
        __builtin_amdgcn_s_barrier();
        ldops(pA, pB, 1, af, bf);
        if (t < 14) stage_half(t + 2, ppA, ppB, 1);
        if (t < 14)       asm volatile("s_waitcnt vmcnt(6)" ::: "memory");
        else if (t == 14) asm volatile("s_waitcnt vmcnt(0)" ::: "memory");
        __builtin_amdgcn_sched_barrier(0);
        __builtin_amdgcn_s_barrier();
        asm volatile("s_waitcnt lgkmcnt(0)" ::: "memory");
        __builtin_amdgcn_sched_barrier(0);
        domfma(af, bf);
        __builtin_amdgcn_sched_barrier(0);
        if (t < 15) {
            __builtin_amdgcn_s_barrier();
            u16* tp;
            tp = pA; pA = pnA; pnA = ppA; ppA = tp;
            tp = pB; pB = pnB; pnB = ppB; ppB = tp;
        }
    }

    if (MODE == 0) {
        const int zsel = by >> 2;  // 0=Q, 1=K, 2=V
        if (zsel < 2) {
            u16* ob = zsel == 0 ? qo : ko;
            const float* bias = zsel == 0 ? b0 : b1;
            const float qs = zsel == 0 ? 0.18033688f : 1.0f;  // log2(e)/8 on Q
#pragma unroll
            for (int m = 0; m < 4; m++) {
#pragma unroll
                for (int n = 0; n < 4; n++) {
                    size_t col = col0 + wn * 64 + n * 16 + l15;
                    size_t colz = col & 1023;
                    float bb = bias[colz];
#pragma unroll
                    for (int r = 0; r < 4; r++) {
                        size_t row = row0 + wm * 64 + m * 16 + lg * 4 + r;
                        ob[row * 1024 + colz] = f2h_bits((acc[m][n][r] + bb) * qs);
                    }
                }
            }
        } else {
            // V: bias + in-LDS transpose -> vt[(b*16+h)*64+d][t]
            u16* TL = &Bs[0][0];  // [256][134] u16 = 68608 B (Bs is 98304 B)
            __syncthreads();
#pragma unroll
            for (int m = 0; m < 4; m++) {
#pragma unroll
                for (int n = 0; n < 4; n++) {
                    int cl = wn * 64 + n * 16 + l15;
                    float bb = b2[(col0 & 1023) + cl];
#pragma unroll
                    for (int r = 0; r < 4; r++) {
                        int rl = wm * 64 + m * 16 + lg * 4 + r;
                        TL[cl * 134 + rl] = f2h_bits(acc[m][n][r] + bb);
                    }
                }
            }
            __syncthreads();
            const int vrl = tid >> 1, th = tid & 1;
            size_t vrow = (row0 >> 11) * 1024 + (col0 & 1023) + vrl;
            const int t0loc = (int)(row0 & 2047) + th * 64;
#pragma unroll
            for (int j = 0; j < 8; j++)
                *(u16x8*)(vt + vrow * 2048 + t0loc + j * 8) =
                    *(const u16x8*)(TL + vrl * 134 + th * 64 + j * 8);
        }
    } else {
        // Wo: y16 = fp16(acc + bias + fp16 residual from xb)
        u16* yo = qo;
        const u16* xres = ko;
#pragma unroll
        for (int m = 0; m < 4; m++) {
#pragma unroll
            for (int n = 0; n < 4; n++) {
                size_t col = col0 + wn * 64 + n * 16 + l15;
                float bb = b0[col];
#pragma unroll
                for (int r = 0; r < 4; r++) {
                    size_t row = row0 + wm * 64 + m * 16 + lg * 4 + r;
                    size_t idx = row * 1024 + col;
                    yo[idx] = f2h_bits(acc[m][n][r] + bb + h2f(xres[idx]));
                }
            }
        }
    }
}

// ------------------------------------------------------------ attention v12
// 8 waves x 32 q = 256 q/block, KV STEP = 128 (two 64-tiles per sync pair):
// halves barriers/vmcnts per kv and doubles the in-wave ILP window (8
// independent QK c-iters, 32 PV MFMAs per body). LDS 64 KB -> 2 blocks/CU.
// K: [128][64] row-XOR swizzle (c8^(rr&7)); V: [64][128] 16-chunk row-XOR
// (vc^(vr&15)), both-sides (pre-swizzled global source + matching read XOR).
// T12 permlane P redistribution; fdot2 psum; exp2-direct softmax; setprio PV.
__global__ __launch_bounds__(512) void attn_kernel(const u16* __restrict__ Q,
                                                   const u16* __restrict__ Kb,
                                                   const u16* __restrict__ Vt,
                                                   u16* __restrict__ ctx) {
    __shared__ u16 Ks[2][128 * 64];
    __shared__ u16 Vs[2][64 * 128];

    const int i = (int)blockIdx.x;
    const int bh = i & 63;
    const int sel = (i >> 6) & 3;
    const int qb = (i < 256) ? (7 - sel) : sel;   // pair (i, i+256) sums to 7
    const int b = bh >> 4, h = bh & 15;
    const int tid = threadIdx.x, lane = tid & 63, wid = tid >> 6;
    const int l15 = lane & 15, lg = lane >> 4;
    const int q0w = qb * 256 + wid * 32;
    const int send = qb * 256;

    const int rr = tid >> 3, c8 = tid & 7;
    const int scw = (c8 ^ (rr & 7)) * 8;            // K source swizzle
    const int vr = tid >> 4, vc = tid & 15;
    const int scv = (vc ^ (vr & 15)) * 8;           // V source swizzle
    const size_t kbase = ((size_t)b * 2048) * 1024 + h * 64 + scw;
    const size_t vbase0 = ((size_t)bh * 64 + vr) * 2048 + scv;
    const size_t vbase1 = ((size_t)bh * 64 + vr + 32) * 2048 + scv;

    f16x8 qv[2][2];
#pragma unroll
    for (int qf = 0; qf < 2; qf++) {
        size_t qoff = ((size_t)b * 2048 + q0w + qf * 16 + l15) * 1024 + h * 64 + lg * 8;
        qv[qf][0] = *(const f16x8*)(Q + qoff);
        qv[qf][1] = *(const f16x8*)(Q + qoff + 32);
    }

    const int swk0 = (lg ^ (l15 & 7)) * 8;
    const int swk1 = ((4 + lg) ^ (l15 & 7)) * 8;

    const h16x2 one2 = {(__fp16)1.0f, (__fp16)1.0f};

    f32x4 acc[2][4] = {};
    float psum[2] = {0.0f, 0.0f};

    // one 128-kv tile: 4 gloads/thread (K rows rr, rr+64; V rows vr, vr+32)
    auto stage = [&](int s, int bf) {
        gload16(Kb + kbase + (size_t)(s + rr) * 1024, Ks[bf] + tid * 8);
        gload16(Kb + kbase + (size_t)(s + rr + 64) * 1024, Ks[bf] + (512 + tid) * 8);
        gload16(Vt + vbase0 + s, Vs[bf] + tid * 8);
        gload16(Vt + vbase1 + s, Vs[bf] + (512 + tid) * 8);
    };

    auto body = [&](int s, int bf, auto maskc) {
        constexpr bool MASK = decltype(maskc)::v;
        u32 W[2][8][2];  // [qf][c][word] packed fp16 P pairs
#pragma unroll
        for (int c = 0; c < 8; c++) {
            const u16* kp = Ks[bf] + (c * 16 + l15) * 64;
            f16x8 kf0 = *(const f16x8*)(kp + swk0);
            f16x8 kf1 = *(const f16x8*)(kp + swk1);
#pragma unroll
            for (int qf = 0; qf < 2; qf++) {
                f32x4 z = {};
                z = __builtin_amdgcn_mfma_f32_16x16x32_f16(kf0, qv[qf][0], z, 0, 0, 0);
                z = __builtin_amdgcn_mfma_f32_16x16x32_f16(kf1, qv[qf][1], z, 0, 0, 0);
                float p0 = __builtin_amdgcn_exp2f(z[0]);
                float p1 = __builtin_amdgcn_exp2f(z[1]);
                float p2 = __builtin_amdgcn_exp2f(z[2]);
                float p3 = __builtin_amdgcn_exp2f(z[3]);
                if (MASK) {
                    int kk = s + c * 16 + lg * 4;
                    int qq = q0w + qf * 16 + l15;
                    p0 = (kk + 0 <= qq) ? p0 : 0.0f;
                    p1 = (kk + 1 <= qq) ? p1 : 0.0f;
                    p2 = (kk + 2 <= qq) ? p2 : 0.0f;
                    p3 = (kk + 3 <= qq) ? p3 : 0.0f;
                }
                h16x2 w0 = __builtin_amdgcn_cvt_pkrtz(p0, p1);
                h16x2 w1 = __builtin_amdgcn_cvt_pkrtz(p2, p3);
                psum[qf] = __builtin_amdgcn_fdot2(w0, one2, psum[qf], false);
                psum[qf] = __builtin_amdgcn_fdot2(w1, one2, psum[qf], false);
                W[qf][c][0] = __builtin_bit_cast(u32, w0);
                W[qf][c][1] = __builtin_bit_cast(u32, w1);
            }
        }
        f16x8 pa0[2][2], pa1[2][2];  // [qf][half]
#pragma unroll
        for (int qf = 0; qf < 2; qf++) {
#pragma unroll
            for (int hf = 0; hf < 2; hf++) {
                const int c0 = hf * 4;
                auto sA = __builtin_amdgcn_permlane32_swap(W[qf][c0][0], W[qf][c0 + 1][0], false, false);
                auto tA = __builtin_amdgcn_permlane16_swap(sA[0], sA[1], false, false);
                auto sB = __builtin_amdgcn_permlane32_swap(W[qf][c0][1], W[qf][c0 + 1][1], false, false);
                auto tB = __builtin_amdgcn_permlane16_swap(sB[0], sB[1], false, false);
                u32x4 v0 = {tA[0], tB[0], tA[1], tB[1]};
                pa0[qf][hf] = __builtin_bit_cast(f16x8, v0);
                auto sC = __builtin_amdgcn_permlane32_swap(W[qf][c0 + 2][0], W[qf][c0 + 3][0], false, false);
                auto tC = __builtin_amdgcn_permlane16_swap(sC[0], sC[1], false, false);
                auto sD = __builtin_amdgcn_permlane32_swap(W[qf][c0 + 2][1], W[qf][c0 + 3][1], false, false);
                auto tD = __builtin_amdgcn_permlane16_swap(sD[0], sD[1], false, false);
                u32x4 v1 = {tC[0], tD[0], tC[1], tD[1]};
                pa1[qf][hf] = __builtin_bit_cast(f16x8, v1);
            }
        }
        __builtin_amdgcn_s_setprio(1);
#pragma unroll
        for (int dt = 0; dt < 4; dt++) {
            const u16* vp = Vs[bf] + (dt * 16 + l15) * 128;
#pragma unroll
            for (int hf = 0; hf < 2; hf++) {
                f16x8 vf0 = *(const f16x8*)(vp + ((hf * 8 + lg) ^ l15) * 8);
                f16x8 vf1 = *(const f16x8*)(vp + ((hf * 8 + 4 + lg) ^ l15) * 8);
#pragma unroll
                for (int qf = 0; qf < 2; qf++) {
                    acc[qf][dt] = __builtin_amdgcn_mfma_f32_16x16x32_f16(
                        pa0[qf][hf], vf0, acc[qf][dt], 0, 0, 0);
                    acc[qf][dt] = __builtin_amdgcn_mfma_f32_16x16x32_f16(
                        pa1[qf][hf], vf1, acc[qf][dt], 0, 0, 0);
                }
            }
        }
        __builtin_amdgcn_s_setprio(0);
    };

    // prologue: 128-tiles at 0 and 128 in flight; wait tile 0 (vmcnt(4))
    stage(0, 0);
    stage(128, 1);
    asm volatile("s_waitcnt vmcnt(4)" ::: "memory");
    __builtin_amdgcn_sched_barrier(0);
    __builtin_amdgcn_s_barrier();

    int cur = 0;
#pragma unroll 1
    for (int s = 0; s < send; s += 128) {
        body(s, cur, BoolTag<false>{});
        __builtin_amdgcn_sched_barrier(0);
        __builtin_amdgcn_s_barrier();              // all waves done reading cur
        stage(s + 256, cur);                        // overwrite cur with s+256
        asm volatile("s_waitcnt vmcnt(4)" ::: "memory");  // s+128 landed (aged)
        __builtin_amdgcn_sched_barrier(0);
        __builtin_amdgcn_s_barrier();
        cur ^= 1;
    }
    // diagonal tail: 2 masked 128-steps; second involves only waves wid>=4.
    body(send, cur, BoolTag<true>{});
    __builtin_amdgcn_sched_barrier(0);
    __builtin_amdgcn_s_barrier();
    asm volatile("s_waitcnt vmcnt(0)" ::: "memory");
    __builtin_amdgcn_sched_barrier(0);
    __builtin_amdgcn_s_barrier();
    if (wid >= 4) body(send + 128, cur ^ 1, BoolTag<true>{});

#pragma unroll
    for (int qf = 0; qf < 2; qf++) {
        psum[qf] += __shfl_xor(psum[qf], 16);
        psum[qf] += __shfl_xor(psum[qf], 32);
    }
#pragma unroll
    for (int qf = 0; qf < 2; qf++) {
        float inv = 1.0f / psum[qf];
#pragma unroll
        for (int r = 0; r < 4; r++) {
            float ir = __shfl(inv, lg * 4 + r);
            size_t row = (size_t)b * 2048 + q0w + qf * 16 + lg * 4 + r;
#pragma unroll
            for (int dt = 0; dt < 4; dt++)
                ctx[row * 1024 + h * 64 + dt * 16 + l15] = f2h_bits(acc[qf][dt][r] * ir);
        }
    }
}

// -------------------------------------------------------------- layer norm
// y in fp16 (16 MB read vs 32), out f32.
__global__ __launch_bounds__(256) void ln_kernel(const u16* __restrict__ y,
                                                 const float* __restrict__ g,
                                                 const float* __restrict__ bb,
                                                 float* __restrict__ out) {
    const int r = blockIdx.x, tid = threadIdx.x;
    u16x4 v4 = *(const u16x4*)(y + (size_t)r * 1024 + tid * 4);
    float vx = h2f(v4[0]), vy = h2f(v4[1]), vz = h2f(v4[2]), vw = h2f(v4[3]);
    float s = vx + vy + vz + vw;
    float sq = vx * vx + vy * vy + vz * vz + vw * vw;
#pragma unroll
    for (int ofs = 1; ofs < 64; ofs <<= 1) {
        s += __shfl_xor(s, ofs);
        sq += __shfl_xor(sq, ofs);
    }
    __shared__ float as[4], aq[4];
    if ((tid & 63) == 0) { as[tid >> 6] = s; aq[tid >> 6] = sq; }
    __syncthreads();
    s = as[0] + as[1] + as[2] + as[3];
    sq = aq[0] + aq[1] + aq[2] + aq[3];
    float mu = s * (1.0f / 1024.0f);
    float var = sq * (1.0f / 1024.0f) - mu * mu;
    float rstd = rsqrtf(var + 1e-5f);
    float4 gv = *(const float4*)(g + tid * 4);
    float4 bv = *(const float4*)(bb + tid * 4);
    float4 o4;
    o4.x = (vx - mu) * rstd * gv.x + bv.x;
    o4.y = (vy - mu) * rstd * gv.y + bv.y;
    o4.z = (vz - mu) * rstd * gv.z + bv.z;
    o4.w = (vw - mu) * rstd * gv.w + bv.w;
    *(float4*)(out + (size_t)r * 1024 + tid * 4) = o4;
}

// ------------------------------------------------------------------ launch
extern "C" void kernel_launch(void* const* d_in, const int* in_sizes, int n_in,
                              void* d_out, int out_size, void* d_ws, size_t ws_size,
                              hipStream_t stream) {
    const float* x  = (const float*)d_in[0];
    const float* Wq = (const float*)d_in[1];
    const float* bq = (const float*)d_in[2];
    const float* Wk = (const float*)d_in[3];
    const float* bk = (const float*)d_in[4];
    const float* Wv = (const float*)d_in[5];
    const float* bv = (const float*)d_in[6];
    const float* Wo = (const float*)d_in[7];
    const float* bo = (const float*)d_in[8];
    const float* lg = (const float*)d_in[9];
    const float* lb = (const float*)d_in[10];
    float* out = (float*)d_out;

    char* ws = (char*)d_ws;
    u16* xb = (u16*)(ws + 0);
    u16* wt = (u16*)(ws + 16777216);
    u16* q  = (u16*)(ws + 25165824);
    u16* k  = (u16*)(ws + 41943040);
    u16* vt = (u16*)(ws + 75497472);
    u16* cx = (u16*)(ws + 92274688);
    u16* y16 = (u16*)(ws + 109051904);

    convert_kernel<<<5120, 256, 0, stream>>>(x, xb, Wq, Wk, Wv, Wo, wt);

    gemm256_kernel<0><<<768, 512, 0, stream>>>(xb, wt, bq, bk, bv, q, k, vt);
    attn_kernel<<<512, 512, 0, stream>>>(q, k, vt, cx);
    gemm256_kernel<1><<<256, 512, 0, stream>>>(cx, wt + 3145728, bo, nullptr,
                                               nullptr, y16, xb, nullptr);
    ln_kernel<<<8192, 256, 0, stream>>>(y16, lg, lb, out);
}